// Round 1
// baseline (948.110 us; speedup 1.0000x reference)
//
#include <hip/hip_runtime.h>
#include <math.h>

// Problem constants
#define D0 768
#define NH 12
#define DHD 64
#define NB 2
#define SQ 1024
#define SCX 256
#define ND 1025            // SQ + 1 (sos prepended)
#define NS 1281            // SCX + ND
#define TT (NB*ND)         // 2050 total h rows
#define TP 2176            // padded rows (34*64)
#define TC (NB*SCX)        // 512 context rows

__device__ __forceinline__ float gelu_new(float x) {
    float x3 = x*x*x;
    float u = 0.7978845608028654f*(x + 0.044715f*x3);
    return 0.5f*x*(1.f + tanhf(u));
}

// Build h = concat(sos, x) per batch. Grid over TT*192 float4s.
__global__ void k_build_h(const float* __restrict__ x, const float* __restrict__ sos,
                          float* __restrict__ h) {
    int idx = blockIdx.x*blockDim.x + threadIdx.x;
    const int total = TT*192;
    if (idx >= total) return;
    int r = idx/192, c4 = idx%192;
    int b = r/ND, t = r%ND;
    float4 v;
    if (t == 0) v = ((const float4*)sos)[c4];
    else        v = ((const float4*)x)[(size_t)(b*SQ + t - 1)*192 + c4];
    ((float4*)h)[(size_t)r*192 + c4] = v;
}

// LayerNorm over 768. Optionally fused residual add (in += add, stored to resid).
// Rows >= nvalid get zero output (pad rows for guard-free GEMM).
__global__ __launch_bounds__(256) void k_ln(const float* __restrict__ in,
                                            const float* __restrict__ add,
                                            const float* __restrict__ g,
                                            const float* __restrict__ beta,
                                            float* __restrict__ out,
                                            float* __restrict__ resid,
                                            int nvalid) {
    int r = blockIdx.x;
    int tid = threadIdx.x;
    if (r >= nvalid) {
        float4 z = make_float4(0.f,0.f,0.f,0.f);
        for (int c4 = tid; c4 < 192; c4 += 256) ((float4*)out)[(size_t)r*192 + c4] = z;
        return;
    }
    const size_t base = (size_t)r*D0;
    float v0 = in[base+tid], v1 = in[base+tid+256], v2 = in[base+tid+512];
    if (add) {
        v0 += add[base+tid]; v1 += add[base+tid+256]; v2 += add[base+tid+512];
        resid[base+tid] = v0; resid[base+tid+256] = v1; resid[base+tid+512] = v2;
    }
    float s = v0+v1+v2;
    float ss = v0*v0 + v1*v1 + v2*v2;
    #pragma unroll
    for (int o = 32; o >= 1; o >>= 1) {
        s  += __shfl_down(s, o);
        ss += __shfl_down(ss, o);
    }
    __shared__ float red[8];
    __shared__ float mv[2];
    int w = tid >> 6;
    if ((tid & 63) == 0) { red[w] = s; red[4+w] = ss; }
    __syncthreads();
    if (tid == 0) {
        float S1 = red[0]+red[1]+red[2]+red[3];
        float S2 = red[4]+red[5]+red[6]+red[7];
        float mean = S1 * (1.f/D0);
        float var  = S2 * (1.f/D0) - mean*mean;
        mv[0] = mean; mv[1] = rsqrtf(var + 1e-5f);
    }
    __syncthreads();
    float mean = mv[0], rstd = mv[1];
    out[base+tid]     = (v0-mean)*rstd*g[tid]     + beta[tid];
    out[base+tid+256] = (v1-mean)*rstd*g[tid+256] + beta[tid+256];
    out[base+tid+512] = (v2-mean)*rstd*g[tid+512] + beta[tid+512];
}

// f32 SIMT GEMM: C[M,N] = A[M,K] @ W[K,N] + bias, EPI=1 applies gelu_new.
// BM=BN=64, BK=16, 256 threads, 4x4 accum/thread. M,N mult of 64; K mult of 16.
template<int EPI>
__global__ __launch_bounds__(256) void k_gemm(const float* __restrict__ A,
                                              const float* __restrict__ W,
                                              const float* __restrict__ bias,
                                              float* __restrict__ C,
                                              int M, int N, int K) {
    __shared__ float As[16][64];
    __shared__ float Ws[16][64];
    const int tid = threadIdx.x;
    const int tx = tid & 15, ty = tid >> 4;
    const int m0 = blockIdx.y * 64, n0 = blockIdx.x * 64;
    const int ar = tid >> 2, ac4 = tid & 3;
    const int wr = tid >> 4, wc4 = tid & 15;
    float acc[4][4] = {};
    for (int k0 = 0; k0 < K; k0 += 16) {
        float4 a4 = *(const float4*)&A[(size_t)(m0+ar)*K + k0 + ac4*4];
        float4 w4 = *(const float4*)&W[(size_t)(k0+wr)*N + n0 + wc4*4];
        __syncthreads();
        As[ac4*4+0][ar] = a4.x;
        As[ac4*4+1][ar] = a4.y;
        As[ac4*4+2][ar] = a4.z;
        As[ac4*4+3][ar] = a4.w;
        *(float4*)&Ws[wr][wc4*4] = w4;
        __syncthreads();
        #pragma unroll
        for (int k = 0; k < 16; ++k) {
            float4 av = *(const float4*)&As[k][ty*4];
            float4 wv = *(const float4*)&Ws[k][tx*4];
            acc[0][0] += av.x*wv.x; acc[0][1] += av.x*wv.y; acc[0][2] += av.x*wv.z; acc[0][3] += av.x*wv.w;
            acc[1][0] += av.y*wv.x; acc[1][1] += av.y*wv.y; acc[1][2] += av.y*wv.z; acc[1][3] += av.y*wv.w;
            acc[2][0] += av.z*wv.x; acc[2][1] += av.z*wv.y; acc[2][2] += av.z*wv.z; acc[2][3] += av.z*wv.w;
            acc[3][0] += av.w*wv.x; acc[3][1] += av.w*wv.y; acc[3][2] += av.w*wv.z; acc[3][3] += av.w*wv.w;
        }
    }
    float4 bv = *(const float4*)&bias[n0 + tx*4];
    #pragma unroll
    for (int i = 0; i < 4; ++i) {
        float o0 = acc[i][0] + bv.x;
        float o1 = acc[i][1] + bv.y;
        float o2 = acc[i][2] + bv.z;
        float o3 = acc[i][3] + bv.w;
        if (EPI == 1) { o0 = gelu_new(o0); o1 = gelu_new(o1); o2 = gelu_new(o2); o3 = gelu_new(o3); }
        *(float4*)&C[(size_t)(m0 + ty*4 + i)*N + n0 + tx*4] = make_float4(o0,o1,o2,o3);
    }
}

// Flash-style attention. Block = (q-tile of 32) x (b,h). 256 threads:
// thread (q = tid>>3, j = tid&7); j owns output dims j*8..j*8+7 and keys j*8..j*8+7 per tile.
// K = [ckv kc | qkv k], V = [ckv vc | qkv v]; mask: key kg <= qidx + SCX.
__global__ __launch_bounds__(256) void k_attn(const float* __restrict__ qkv,
                                              const float* __restrict__ ckv,
                                              float* __restrict__ attno) {
    const int qt = blockIdx.x;
    const int bh = blockIdx.y;
    const int b = bh / NH, hh = bh % NH;
    const int tid = threadIdx.x;
    const int lane = tid & 63;
    const int q = tid >> 3;
    const int j = tid & 7;
    const int q0 = qt * 32;
    const int nq = min(32, ND - q0);
    const int qidx = q0 + q;

    __shared__ float Qs[32][64];   // xor-swizzled by row&7 (f4 granularity)
    __shared__ float Ks[64][64];   // xor-swizzled by row>>3
    __shared__ float Vs[64][64];   // xor-swizzled by row&7

    for (int l = tid; l < 32*16; l += 256) {
        int qi = l >> 4, c4 = l & 15;
        float4 v = make_float4(0.f,0.f,0.f,0.f);
        if (q0 + qi < ND)
            v = *(const float4*)&qkv[(size_t)(b*ND + q0 + qi)*2304 + hh*64 + c4*4];
        *(float4*)&Qs[qi][(c4 ^ (qi & 7))*4] = v;
    }

    float m = -1e30f, lsum = 0.f;
    float acc[8];
    #pragma unroll
    for (int d = 0; d < 8; ++d) acc[d] = 0.f;

    const int kmax = q0 + nq - 1 + SCX;
    const int ntiles = kmax/64 + 1;

    for (int kt = 0; kt < ntiles; ++kt) {
        __syncthreads();
        for (int l = tid; l < 64*16; l += 256) {
            int kr = l >> 4, c4 = l & 15;
            int kg = kt*64 + kr;
            float4 kv = make_float4(0.f,0.f,0.f,0.f), vv = kv;
            if (kg < SCX) {
                const float* src = &ckv[(size_t)(b*SCX + kg)*1536 + hh*64 + c4*4];
                kv = *(const float4*)src;
                vv = *(const float4*)(src + 768);
            } else if (kg < NS) {
                const float* src = &qkv[(size_t)(b*ND + kg - SCX)*2304 + 768 + hh*64 + c4*4];
                kv = *(const float4*)src;
                vv = *(const float4*)(src + 768);
            }
            *(float4*)&Ks[kr][(c4 ^ (kr >> 3))*4] = kv;
            *(float4*)&Vs[kr][(c4 ^ (kr & 7))*4] = vv;
        }
        __syncthreads();

        float sc[8];
        #pragma unroll
        for (int kk = 0; kk < 8; ++kk) sc[kk] = 0.f;
        #pragma unroll
        for (int c4 = 0; c4 < 16; ++c4) {
            float4 qv = *(const float4*)&Qs[q][(c4 ^ (q & 7))*4];
            #pragma unroll
            for (int kk = 0; kk < 8; ++kk) {
                float4 kv = *(const float4*)&Ks[j*8+kk][(c4 ^ j)*4];
                sc[kk] += qv.x*kv.x + qv.y*kv.y + qv.z*kv.z + qv.w*kv.w;
            }
        }
        const int kbase = kt*64;
        #pragma unroll
        for (int kk = 0; kk < 8; ++kk) {
            int kg = kbase + j*8 + kk;
            sc[kk] = (kg <= qidx + SCX) ? sc[kk]*0.125f : -1e30f;
        }
        float tmax = sc[0];
        #pragma unroll
        for (int kk = 1; kk < 8; ++kk) tmax = fmaxf(tmax, sc[kk]);
        #pragma unroll
        for (int o = 1; o < 8; o <<= 1) tmax = fmaxf(tmax, __shfl_xor(tmax, o));
        float mnew = fmaxf(m, tmax);
        float scale = __expf(m - mnew);
        float p[8], psum = 0.f;
        #pragma unroll
        for (int kk = 0; kk < 8; ++kk) { p[kk] = __expf(sc[kk] - mnew); psum += p[kk]; }
        #pragma unroll
        for (int o = 1; o < 8; o <<= 1) psum += __shfl_xor(psum, o);
        lsum = lsum*scale + psum;
        m = mnew;
        #pragma unroll
        for (int d = 0; d < 8; ++d) acc[d] *= scale;
        #pragma unroll
        for (int src = 0; src < 8; ++src) {
            #pragma unroll
            for (int kk = 0; kk < 8; ++kk) {
                float pk = __shfl(p[kk], (lane & 56) + src);
                int k = src*8 + kk;
                int s2 = k & 7;
                float4 v0 = *(const float4*)&Vs[k][(((j*2)   ^ s2))*4];
                float4 v1 = *(const float4*)&Vs[k][(((j*2+1) ^ s2))*4];
                acc[0] += pk*v0.x; acc[1] += pk*v0.y; acc[2] += pk*v0.z; acc[3] += pk*v0.w;
                acc[4] += pk*v1.x; acc[5] += pk*v1.y; acc[6] += pk*v1.z; acc[7] += pk*v1.w;
            }
        }
    }
    if (q < nq) {
        float inv = 1.f / lsum;
        float* dst = &attno[(size_t)(b*ND + qidx)*D0 + hh*64 + j*8];
        *(float4*)dst     = make_float4(acc[0]*inv, acc[1]*inv, acc[2]*inv, acc[3]*inv);
        *(float4*)(dst+4) = make_float4(acc[4]*inv, acc[5]*inv, acc[6]*inv, acc[7]*inv);
    }
}

// out[b,t,:] = h[b, t+1, :] + mproj[b, t+1, :]   (drop sos row)
__global__ void k_final(const float* __restrict__ h, const float* __restrict__ mp,
                        float* __restrict__ out) {
    int idx = blockIdx.x*blockDim.x + threadIdx.x;
    const int total = NB*SQ*192;
    if (idx >= total) return;
    int r = idx/192, c4 = idx%192;
    int b = r/SQ, t = r%SQ;
    size_t hr = (size_t)(b*ND + t + 1)*192 + c4;
    float4 hv = ((const float4*)h)[hr];
    float4 mv = ((const float4*)mp)[hr];
    ((float4*)out)[idx] = make_float4(hv.x+mv.x, hv.y+mv.y, hv.z+mv.z, hv.w+mv.w);
}

extern "C" void kernel_launch(void* const* d_in, const int* in_sizes, int n_in,
                              void* d_out, int out_size, void* d_ws, size_t ws_size,
                              hipStream_t stream) {
    const float* x     = (const float*)d_in[0];
    const float* ctx   = (const float*)d_in[1];
    const float* sos   = (const float*)d_in[2];
    const float* ln1g  = (const float*)d_in[3];
    const float* ln1b  = (const float*)d_in[4];
    const float* Wat   = (const float*)d_in[5];
    const float* bat   = (const float*)d_in[6];
    const float* Wref  = (const float*)d_in[7];
    const float* bref  = (const float*)d_in[8];
    const float* Wpj   = (const float*)d_in[9];
    const float* bpj   = (const float*)d_in[10];
    const float* ln2g  = (const float*)d_in[11];
    const float* ln2b  = (const float*)d_in[12];
    const float* Wfc   = (const float*)d_in[13];
    const float* bfc   = (const float*)d_in[14];
    const float* Wmp   = (const float*)d_in[15];
    const float* bmp   = (const float*)d_in[16];
    float* out = (float*)d_out;

    float* ws    = (float*)d_ws;
    float* h     = ws;                        // TP*768  residual stream
    float* hl    = h     + (size_t)TP*768;    // TP*768  ln1 out, reused as ln2 out
    float* qkv   = hl    + (size_t)TP*768;    // TP*2304
    float* ckv   = qkv   + (size_t)TP*2304;   // TC*1536
    float* attno = ckv   + (size_t)TC*1536;   // TP*768
    float* aproj = attno + (size_t)TP*768;    // TP*768, reused as mproj out
    float* mfc   = aproj + (size_t)TP*768;    // TP*3072

    k_build_h<<<dim3((TT*192 + 255)/256), dim3(256), 0, stream>>>(x, sos, h);
    k_ln<<<dim3(TP), dim3(256), 0, stream>>>(h, nullptr, ln1g, ln1b, hl, nullptr, TT);
    k_gemm<0><<<dim3(2304/64, TP/64), dim3(256), 0, stream>>>(hl, Wat, bat, qkv, TP, 2304, 768);
    k_gemm<0><<<dim3(1536/64, TC/64), dim3(256), 0, stream>>>(ctx, Wref, bref, ckv, TC, 1536, 768);
    k_attn<<<dim3(33, NB*NH), dim3(256), 0, stream>>>(qkv, ckv, attno);
    k_gemm<0><<<dim3(768/64, TP/64), dim3(256), 0, stream>>>(attno, Wpj, bpj, aproj, TP, 768, 768);
    k_ln<<<dim3(TP), dim3(256), 0, stream>>>(h, aproj, ln2g, ln2b, hl, h, TT);
    k_gemm<1><<<dim3(3072/64, TP/64), dim3(256), 0, stream>>>(hl, Wfc, bfc, mfc, TP, 3072, 768);
    k_gemm<0><<<dim3(768/64, TP/64), dim3(256), 0, stream>>>(mfc, Wmp, bmp, aproj, TP, 768, 3072);
    k_final<<<dim3((NB*SQ*192 + 255)/256), dim3(256), 0, stream>>>(h, aproj, out);
}

// Round 2
// 507.936 us; speedup vs baseline: 1.8666x; 1.8666x over previous
//
#include <hip/hip_runtime.h>
#include <math.h>

// Problem constants
#define D0 768
#define NH 12
#define DHD 64
#define NB 2
#define SQ 1024
#define SCX 256
#define ND 1025            // SQ + 1 (sos prepended)
#define NS 1281            // SCX + ND
#define TT (NB*ND)         // 2050 total h rows
#define TP 2176            // padded rows (17*128)
#define TC (NB*SCX)        // 512 context rows

typedef __attribute__((ext_vector_type(8))) short bf16x8;   // 8 bf16 in 4 VGPRs
typedef __attribute__((ext_vector_type(4))) float f32x4;

typedef const __attribute__((address_space(1))) unsigned int* gptr_t;
typedef __attribute__((address_space(3))) unsigned int* lptr_t;

__device__ __forceinline__ unsigned short f2bf(float f) {
    union { float f; unsigned u; } v; v.f = f;
    unsigned r = v.u + 0x7FFFu + ((v.u >> 16) & 1u);
    return (unsigned short)(r >> 16);
}

__device__ __forceinline__ float gelu_new(float x) {
    float x3 = x*x*x;
    float u = 0.7978845608028654f*(x + 0.044715f*x3);
    return 0.5f*x*(1.f + tanhf(u));
}

// Build h = concat(sos, x) per batch. Grid over TT*192 float4s.
__global__ void k_build_h(const float* __restrict__ x, const float* __restrict__ sos,
                          float* __restrict__ h) {
    int idx = blockIdx.x*blockDim.x + threadIdx.x;
    const int total = TT*192;
    if (idx >= total) return;
    int r = idx/192, c4 = idx%192;
    int b = r/ND, t = r%ND;
    float4 v;
    if (t == 0) v = ((const float4*)sos)[c4];
    else        v = ((const float4*)x)[(size_t)(b*SQ + t - 1)*192 + c4];
    ((float4*)h)[(size_t)r*192 + c4] = v;
}

// f32 -> bf16 elementwise, 8 elems/thread. n8 = total/8.
__global__ void k_cvt_bf(const float* __restrict__ in, unsigned short* __restrict__ out, int n8) {
    int i = blockIdx.x*blockDim.x + threadIdx.x;
    if (i >= n8) return;
    float4 a = ((const float4*)in)[i*2];
    float4 b = ((const float4*)in)[i*2+1];
    uint4 o;
    o.x = (unsigned)f2bf(a.x) | ((unsigned)f2bf(a.y) << 16);
    o.y = (unsigned)f2bf(a.z) | ((unsigned)f2bf(a.w) << 16);
    o.z = (unsigned)f2bf(b.x) | ((unsigned)f2bf(b.y) << 16);
    o.w = (unsigned)f2bf(b.z) | ((unsigned)f2bf(b.w) << 16);
    ((uint4*)out)[i] = o;
}

// W[K][N] f32 -> Wt[N][K] bf16. Grid (N/32, K/32), block 256.
__global__ __launch_bounds__(256) void k_transpose_bf(const float* __restrict__ W,
                                                      unsigned short* __restrict__ Wt,
                                                      int K, int N) {
    __shared__ float t[32][33];
    const int n0 = blockIdx.x*32, k0 = blockIdx.y*32;
    const int r = threadIdx.x >> 3, c4 = (threadIdx.x & 7)*4;
    float4 v = *(const float4*)&W[(size_t)(k0+r)*N + n0 + c4];
    t[r][c4+0]=v.x; t[r][c4+1]=v.y; t[r][c4+2]=v.z; t[r][c4+3]=v.w;
    __syncthreads();
    ushort4 o;
    o.x = f2bf(t[c4+0][r]); o.y = f2bf(t[c4+1][r]);
    o.z = f2bf(t[c4+2][r]); o.w = f2bf(t[c4+3][r]);
    *(ushort4*)&Wt[(size_t)(n0+r)*K + k0 + c4] = o;
}

// LayerNorm over 768, bf16 output. Optional fused residual add (in += add -> resid).
// Rows >= nvalid get zero output (pad rows for guard-free GEMM).
__global__ __launch_bounds__(256) void k_ln(const float* __restrict__ in,
                                            const float* __restrict__ add,
                                            const float* __restrict__ g,
                                            const float* __restrict__ beta,
                                            unsigned short* __restrict__ out,
                                            float* __restrict__ resid,
                                            int nvalid) {
    int r = blockIdx.x;
    int tid = threadIdx.x;
    const size_t base = (size_t)r*D0;
    if (r >= nvalid) {
        out[base+tid] = 0; out[base+tid+256] = 0; out[base+tid+512] = 0;
        return;
    }
    float v0 = in[base+tid], v1 = in[base+tid+256], v2 = in[base+tid+512];
    if (add) {
        v0 += add[base+tid]; v1 += add[base+tid+256]; v2 += add[base+tid+512];
        resid[base+tid] = v0; resid[base+tid+256] = v1; resid[base+tid+512] = v2;
    }
    float s = v0+v1+v2;
    float ss = v0*v0 + v1*v1 + v2*v2;
    #pragma unroll
    for (int o = 32; o >= 1; o >>= 1) {
        s  += __shfl_down(s, o);
        ss += __shfl_down(ss, o);
    }
    __shared__ float red[8];
    __shared__ float mv[2];
    int w = tid >> 6;
    if ((tid & 63) == 0) { red[w] = s; red[4+w] = ss; }
    __syncthreads();
    if (tid == 0) {
        float S1 = red[0]+red[1]+red[2]+red[3];
        float S2 = red[4]+red[5]+red[6]+red[7];
        float mean = S1 * (1.f/D0);
        float var  = S2 * (1.f/D0) - mean*mean;
        mv[0] = mean; mv[1] = rsqrtf(var + 1e-5f);
    }
    __syncthreads();
    float mean = mv[0], rstd = mv[1];
    out[base+tid]     = f2bf((v0-mean)*rstd*g[tid]     + beta[tid]);
    out[base+tid+256] = f2bf((v1-mean)*rstd*g[tid+256] + beta[tid+256]);
    out[base+tid+512] = f2bf((v2-mean)*rstd*g[tid+512] + beta[tid+512]);
}

// bf16 MFMA GEMM (m97 structure): C[M,N] = A[M,K] @ Bt[N,K]^T + bias.
// 128x128 tile, BK=32, 256 threads = 4 waves (2x2), 4x4 16x16 frags/wave.
// A, Bt are bf16 (ushort). M%128==0, N%128==0, K%32==0.
template<int GELU, int OUTBF>
__global__ __launch_bounds__(256) void k_gemm_bf16(const unsigned short* __restrict__ A,
                                                   const unsigned short* __restrict__ Bt,
                                                   const float* __restrict__ bias,
                                                   void* __restrict__ Cv,
                                                   int M, int N, int K) {
    __shared__ unsigned short As[128*32];
    __shared__ unsigned short Bs[128*32];
    const int tid = threadIdx.x;
    const int w = tid >> 6;          // wave 0..3
    const int l = tid & 63;
    const int wm = w >> 1, wn = w & 1;
    const int m0 = blockIdx.y * 128, n0 = blockIdx.x * 128;
    const int lr = l >> 2;           // 0..15: row within 16-row segment
    const int lk = (l & 3) * 8;      // k offset (elements)

    f32x4 acc[4][4] = {};

    for (int k0 = 0; k0 < K; k0 += 32) {
        __syncthreads();
        #pragma unroll
        for (int i = 0; i < 2; ++i) {
            int seg = i*4 + w;
            const unsigned short* ga = A  + (size_t)(m0 + seg*16 + lr)*K + k0 + lk;
            const unsigned short* gb = Bt + (size_t)(n0 + seg*16 + lr)*K + k0 + lk;
            __builtin_amdgcn_global_load_lds((gptr_t)ga, (lptr_t)(As + seg*512), 16, 0, 0);
            __builtin_amdgcn_global_load_lds((gptr_t)gb, (lptr_t)(Bs + seg*512), 16, 0, 0);
        }
        __syncthreads();   // compiler emits vmcnt(0) drain before barrier -> LDS ready
        bf16x8 a[4], b[4];
        #pragma unroll
        for (int mi = 0; mi < 4; ++mi)
            a[mi] = *(const bf16x8*)&As[(wm*64 + mi*16 + (l & 15))*32 + (l >> 4)*8];
        #pragma unroll
        for (int ni = 0; ni < 4; ++ni)
            b[ni] = *(const bf16x8*)&Bs[(wn*64 + ni*16 + (l & 15))*32 + (l >> 4)*8];
        #pragma unroll
        for (int mi = 0; mi < 4; ++mi)
            #pragma unroll
            for (int ni = 0; ni < 4; ++ni)
                acc[mi][ni] = __builtin_amdgcn_mfma_f32_16x16x32_bf16(a[mi], b[ni], acc[mi][ni], 0, 0, 0);
    }

    // Epilogue. C/D layout (HW-verified): col = lane&15, row = (lane>>4)*4 + reg.
    float* Cf = (float*)Cv;
    unsigned short* Cb = (unsigned short*)Cv;
    const int rbase = m0 + wm*64 + (l >> 4)*4;
    const int cbase = n0 + wn*64 + (l & 15);
    #pragma unroll
    for (int ni = 0; ni < 4; ++ni) {
        int col = cbase + ni*16;
        float bv = bias[col];
        #pragma unroll
        for (int mi = 0; mi < 4; ++mi) {
            #pragma unroll
            for (int r = 0; r < 4; ++r) {
                int row = rbase + mi*16 + r;
                float v = acc[mi][ni][r] + bv;
                if (GELU) v = gelu_new(v);
                if (OUTBF) Cb[(size_t)row*N + col] = f2bf(v);
                else       Cf[(size_t)row*N + col] = v;
            }
        }
    }
}

// Flash-style attention (unchanged math), bf16 output.
__global__ __launch_bounds__(256) void k_attn(const float* __restrict__ qkv,
                                              const float* __restrict__ ckv,
                                              unsigned short* __restrict__ attnob) {
    const int qt = blockIdx.x;
    const int bh = blockIdx.y;
    const int b = bh / NH, hh = bh % NH;
    const int tid = threadIdx.x;
    const int lane = tid & 63;
    const int q = tid >> 3;
    const int j = tid & 7;
    const int q0 = qt * 32;
    const int nq = min(32, ND - q0);
    const int qidx = q0 + q;

    __shared__ float Qs[32][64];   // xor-swizzled by row&7 (f4 granularity)
    __shared__ float Ks[64][64];   // xor-swizzled by row>>3
    __shared__ float Vs[64][64];   // xor-swizzled by row&7

    for (int l = tid; l < 32*16; l += 256) {
        int qi = l >> 4, c4 = l & 15;
        float4 v = make_float4(0.f,0.f,0.f,0.f);
        if (q0 + qi < ND)
            v = *(const float4*)&qkv[(size_t)(b*ND + q0 + qi)*2304 + hh*64 + c4*4];
        *(float4*)&Qs[qi][(c4 ^ (qi & 7))*4] = v;
    }

    float m = -1e30f, lsum = 0.f;
    float acc[8];
    #pragma unroll
    for (int d = 0; d < 8; ++d) acc[d] = 0.f;

    const int kmax = q0 + nq - 1 + SCX;
    const int ntiles = kmax/64 + 1;

    for (int kt = 0; kt < ntiles; ++kt) {
        __syncthreads();
        for (int l = tid; l < 64*16; l += 256) {
            int kr = l >> 4, c4 = l & 15;
            int kg = kt*64 + kr;
            float4 kv = make_float4(0.f,0.f,0.f,0.f), vv = kv;
            if (kg < SCX) {
                const float* src = &ckv[(size_t)(b*SCX + kg)*1536 + hh*64 + c4*4];
                kv = *(const float4*)src;
                vv = *(const float4*)(src + 768);
            } else if (kg < NS) {
                const float* src = &qkv[(size_t)(b*ND + kg - SCX)*2304 + 768 + hh*64 + c4*4];
                kv = *(const float4*)src;
                vv = *(const float4*)(src + 768);
            }
            *(float4*)&Ks[kr][(c4 ^ (kr >> 3))*4] = kv;
            *(float4*)&Vs[kr][(c4 ^ (kr & 7))*4] = vv;
        }
        __syncthreads();

        float sc[8];
        #pragma unroll
        for (int kk = 0; kk < 8; ++kk) sc[kk] = 0.f;
        #pragma unroll
        for (int c4 = 0; c4 < 16; ++c4) {
            float4 qv = *(const float4*)&Qs[q][(c4 ^ (q & 7))*4];
            #pragma unroll
            for (int kk = 0; kk < 8; ++kk) {
                float4 kv = *(const float4*)&Ks[j*8+kk][(c4 ^ j)*4];
                sc[kk] += qv.x*kv.x + qv.y*kv.y + qv.z*kv.z + qv.w*kv.w;
            }
        }
        const int kbase = kt*64;
        #pragma unroll
        for (int kk = 0; kk < 8; ++kk) {
            int kg = kbase + j*8 + kk;
            sc[kk] = (kg <= qidx + SCX) ? sc[kk]*0.125f : -1e30f;
        }
        float tmax = sc[0];
        #pragma unroll
        for (int kk = 1; kk < 8; ++kk) tmax = fmaxf(tmax, sc[kk]);
        #pragma unroll
        for (int o = 1; o < 8; o <<= 1) tmax = fmaxf(tmax, __shfl_xor(tmax, o));
        float mnew = fmaxf(m, tmax);
        float scale = __expf(m - mnew);
        float p[8], psum = 0.f;
        #pragma unroll
        for (int kk = 0; kk < 8; ++kk) { p[kk] = __expf(sc[kk] - mnew); psum += p[kk]; }
        #pragma unroll
        for (int o = 1; o < 8; o <<= 1) psum += __shfl_xor(psum, o);
        lsum = lsum*scale + psum;
        m = mnew;
        #pragma unroll
        for (int d = 0; d < 8; ++d) acc[d] *= scale;
        #pragma unroll
        for (int src = 0; src < 8; ++src) {
            #pragma unroll
            for (int kk = 0; kk < 8; ++kk) {
                float pk = __shfl(p[kk], (lane & 56) + src);
                int k = src*8 + kk;
                int s2 = k & 7;
                float4 v0 = *(const float4*)&Vs[k][(((j*2)   ^ s2))*4];
                float4 v1 = *(const float4*)&Vs[k][(((j*2+1) ^ s2))*4];
                acc[0] += pk*v0.x; acc[1] += pk*v0.y; acc[2] += pk*v0.z; acc[3] += pk*v0.w;
                acc[4] += pk*v1.x; acc[5] += pk*v1.y; acc[6] += pk*v1.z; acc[7] += pk*v1.w;
            }
        }
    }
    if (q < nq) {
        float inv = 1.f / lsum;
        unsigned short* dst = &attnob[(size_t)(b*ND + qidx)*D0 + hh*64 + j*8];
        uint4 o;
        o.x = (unsigned)f2bf(acc[0]*inv) | ((unsigned)f2bf(acc[1]*inv) << 16);
        o.y = (unsigned)f2bf(acc[2]*inv) | ((unsigned)f2bf(acc[3]*inv) << 16);
        o.z = (unsigned)f2bf(acc[4]*inv) | ((unsigned)f2bf(acc[5]*inv) << 16);
        o.w = (unsigned)f2bf(acc[6]*inv) | ((unsigned)f2bf(acc[7]*inv) << 16);
        *(uint4*)dst = o;
    }
}

// out[b,t,:] = h[b, t+1, :] + mproj[b, t+1, :]   (drop sos row)
__global__ void k_final(const float* __restrict__ h, const float* __restrict__ mp,
                        float* __restrict__ out) {
    int idx = blockIdx.x*blockDim.x + threadIdx.x;
    const int total = NB*SQ*192;
    if (idx >= total) return;
    int r = idx/192, c4 = idx%192;
    int b = r/SQ, t = r%SQ;
    size_t hr = (size_t)(b*ND + t + 1)*192 + c4;
    float4 hv = ((const float4*)h)[hr];
    float4 mv = ((const float4*)mp)[hr];
    ((float4*)out)[idx] = make_float4(hv.x+mv.x, hv.y+mv.y, hv.z+mv.z, hv.w+mv.w);
}

extern "C" void kernel_launch(void* const* d_in, const int* in_sizes, int n_in,
                              void* d_out, int out_size, void* d_ws, size_t ws_size,
                              hipStream_t stream) {
    const float* x     = (const float*)d_in[0];
    const float* ctx   = (const float*)d_in[1];
    const float* sos   = (const float*)d_in[2];
    const float* ln1g  = (const float*)d_in[3];
    const float* ln1b  = (const float*)d_in[4];
    const float* Wat   = (const float*)d_in[5];
    const float* bat   = (const float*)d_in[6];
    const float* Wref  = (const float*)d_in[7];
    const float* bref  = (const float*)d_in[8];
    const float* Wpj   = (const float*)d_in[9];
    const float* bpj   = (const float*)d_in[10];
    const float* ln2g  = (const float*)d_in[11];
    const float* ln2b  = (const float*)d_in[12];
    const float* Wfc   = (const float*)d_in[13];
    const float* bfc   = (const float*)d_in[14];
    const float* Wmp   = (const float*)d_in[15];
    const float* bmp   = (const float*)d_in[16];
    float* out = (float*)d_out;

    char* p = (char*)d_ws;
    float* h      = (float*)p;  p += (size_t)TP*768*4;
    float* qkv    = (float*)p;  p += (size_t)TP*2304*4;
    float* ckv    = (float*)p;  p += (size_t)TC*1536*4;
    float* aproj  = (float*)p;  p += (size_t)TP*768*4;   // proj out, reused for mproj out
    unsigned short* hlb    = (unsigned short*)p;  p += (size_t)TP*768*2;
    unsigned short* attnob = (unsigned short*)p;  p += (size_t)TP*768*2;
    unsigned short* mfcb   = (unsigned short*)p;  p += (size_t)TP*3072*2;
    unsigned short* ctxb   = (unsigned short*)p;  p += (size_t)TC*768*2;
    unsigned short* WatT   = (unsigned short*)p;  p += (size_t)2304*768*2;
    unsigned short* WrefT  = (unsigned short*)p;  p += (size_t)1536*768*2;
    unsigned short* WpjT   = (unsigned short*)p;  p += (size_t)768*768*2;
    unsigned short* WfcT   = (unsigned short*)p;  p += (size_t)3072*768*2;
    unsigned short* WmpT   = (unsigned short*)p;  p += (size_t)768*3072*2;

    // Weight transposes f32 [K][N] -> bf16 [N][K]
    k_transpose_bf<<<dim3(2304/32, 768/32),  dim3(256), 0, stream>>>(Wat, WatT, 768, 2304);
    k_transpose_bf<<<dim3(1536/32, 768/32),  dim3(256), 0, stream>>>(Wref, WrefT, 768, 1536);
    k_transpose_bf<<<dim3(768/32,  768/32),  dim3(256), 0, stream>>>(Wpj, WpjT, 768, 768);
    k_transpose_bf<<<dim3(3072/32, 768/32),  dim3(256), 0, stream>>>(Wfc, WfcT, 768, 3072);
    k_transpose_bf<<<dim3(768/32,  3072/32), dim3(256), 0, stream>>>(Wmp, WmpT, 3072, 768);

    k_build_h<<<dim3((TT*192 + 255)/256), dim3(256), 0, stream>>>(x, sos, h);
    k_cvt_bf<<<dim3((TC*768/8 + 255)/256), dim3(256), 0, stream>>>(ctx, ctxb, TC*768/8);

    k_ln<<<dim3(TP), dim3(256), 0, stream>>>(h, nullptr, ln1g, ln1b, hlb, nullptr, TT);
    k_gemm_bf16<0,0><<<dim3(2304/128, TP/128), dim3(256), 0, stream>>>(hlb, WatT, bat, qkv, TP, 2304, 768);
    k_gemm_bf16<0,0><<<dim3(1536/128, TC/128), dim3(256), 0, stream>>>(ctxb, WrefT, bref, ckv, TC, 1536, 768);
    k_attn<<<dim3(33, NB*NH), dim3(256), 0, stream>>>(qkv, ckv, attnob);
    k_gemm_bf16<0,0><<<dim3(768/128, TP/128), dim3(256), 0, stream>>>(attnob, WpjT, bpj, aproj, TP, 768, 768);
    k_ln<<<dim3(TP), dim3(256), 0, stream>>>(h, aproj, ln2g, ln2b, hlb, h, TT);
    k_gemm_bf16<1,1><<<dim3(3072/128, TP/128), dim3(256), 0, stream>>>(hlb, WfcT, bfc, mfcb, TP, 3072, 768);
    k_gemm_bf16<0,0><<<dim3(768/128, TP/128), dim3(256), 0, stream>>>(mfcb, WmpT, bmp, aproj, TP, 768, 3072);
    k_final<<<dim3((NB*SQ*192 + 255)/256), dim3(256), 0, stream>>>(h, aproj, out);
}

// Round 3
// 362.177 us; speedup vs baseline: 2.6178x; 1.4025x over previous
//
#include <hip/hip_runtime.h>
#include <math.h>

// Problem constants
#define D0 768
#define NH 12
#define DHD 64
#define NB 2
#define SQ 1024
#define SCX 256
#define ND 1025            // SQ + 1 (sos prepended)
#define NS 1281            // SCX + ND
#define TT (NB*ND)         // 2050 total h rows
#define TP 2176            // padded rows (17*128)
#define TC (NB*SCX)        // 512 context rows

typedef __attribute__((ext_vector_type(8))) short bf16x8;   // 8 bf16 in 4 VGPRs
typedef __attribute__((ext_vector_type(4))) float f32x4;

typedef const __attribute__((address_space(1))) unsigned int* gptr_t;
typedef __attribute__((address_space(3))) unsigned int* lptr_t;

__device__ __forceinline__ unsigned short f2bf(float f) {
    union { float f; unsigned u; } v; v.f = f;
    unsigned r = v.u + 0x7FFFu + ((v.u >> 16) & 1u);
    return (unsigned short)(r >> 16);
}

__device__ __forceinline__ float gelu_new(float x) {
    float x3 = x*x*x;
    float u = 0.7978845608028654f*(x + 0.044715f*x3);
    return 0.5f*x*(1.f + tanhf(u));
}

// Build h = concat(sos, x) per batch. Grid over TT*192 float4s.
__global__ void k_build_h(const float* __restrict__ x, const float* __restrict__ sos,
                          float* __restrict__ h) {
    int idx = blockIdx.x*blockDim.x + threadIdx.x;
    const int total = TT*192;
    if (idx >= total) return;
    int r = idx/192, c4 = idx%192;
    int b = r/ND, t = r%ND;
    float4 v;
    if (t == 0) v = ((const float4*)sos)[c4];
    else        v = ((const float4*)x)[(size_t)(b*SQ + t - 1)*192 + c4];
    ((float4*)h)[(size_t)r*192 + c4] = v;
}

// f32 -> bf16 elementwise, 8 elems/thread. n8 = total/8.
__global__ void k_cvt_bf(const float* __restrict__ in, unsigned short* __restrict__ out, int n8) {
    int i = blockIdx.x*blockDim.x + threadIdx.x;
    if (i >= n8) return;
    float4 a = ((const float4*)in)[i*2];
    float4 b = ((const float4*)in)[i*2+1];
    uint4 o;
    o.x = (unsigned)f2bf(a.x) | ((unsigned)f2bf(a.y) << 16);
    o.y = (unsigned)f2bf(a.z) | ((unsigned)f2bf(a.w) << 16);
    o.z = (unsigned)f2bf(b.x) | ((unsigned)f2bf(b.y) << 16);
    o.w = (unsigned)f2bf(b.z) | ((unsigned)f2bf(b.w) << 16);
    ((uint4*)out)[i] = o;
}

// W[K][N] f32 -> Wt[N][K] bf16. Grid (N/32, K/32), block 256.
__global__ __launch_bounds__(256) void k_transpose_bf(const float* __restrict__ W,
                                                      unsigned short* __restrict__ Wt,
                                                      int K, int N) {
    __shared__ float t[32][33];
    const int n0 = blockIdx.x*32, k0 = blockIdx.y*32;
    const int r = threadIdx.x >> 3, c4 = (threadIdx.x & 7)*4;
    float4 v = *(const float4*)&W[(size_t)(k0+r)*N + n0 + c4];
    t[r][c4+0]=v.x; t[r][c4+1]=v.y; t[r][c4+2]=v.z; t[r][c4+3]=v.w;
    __syncthreads();
    ushort4 o;
    o.x = f2bf(t[c4+0][r]); o.y = f2bf(t[c4+1][r]);
    o.z = f2bf(t[c4+2][r]); o.w = f2bf(t[c4+3][r]);
    *(ushort4*)&Wt[(size_t)(n0+r)*K + k0 + c4] = o;
}

// LayerNorm over 768, bf16 output. Optional fused residual add (in += add -> resid).
__global__ __launch_bounds__(256) void k_ln(const float* __restrict__ in,
                                            const float* __restrict__ add,
                                            const float* __restrict__ g,
                                            const float* __restrict__ beta,
                                            unsigned short* __restrict__ out,
                                            float* __restrict__ resid,
                                            int nvalid) {
    int r = blockIdx.x;
    int tid = threadIdx.x;
    const size_t base = (size_t)r*D0;
    if (r >= nvalid) {
        out[base+tid] = 0; out[base+tid+256] = 0; out[base+tid+512] = 0;
        return;
    }
    float v0 = in[base+tid], v1 = in[base+tid+256], v2 = in[base+tid+512];
    if (add) {
        v0 += add[base+tid]; v1 += add[base+tid+256]; v2 += add[base+tid+512];
        resid[base+tid] = v0; resid[base+tid+256] = v1; resid[base+tid+512] = v2;
    }
    float s = v0+v1+v2;
    float ss = v0*v0 + v1*v1 + v2*v2;
    #pragma unroll
    for (int o = 32; o >= 1; o >>= 1) {
        s  += __shfl_down(s, o);
        ss += __shfl_down(ss, o);
    }
    __shared__ float red[8];
    __shared__ float mv[2];
    int w = tid >> 6;
    if ((tid & 63) == 0) { red[w] = s; red[4+w] = ss; }
    __syncthreads();
    if (tid == 0) {
        float S1 = red[0]+red[1]+red[2]+red[3];
        float S2 = red[4]+red[5]+red[6]+red[7];
        float mean = S1 * (1.f/D0);
        float var  = S2 * (1.f/D0) - mean*mean;
        mv[0] = mean; mv[1] = rsqrtf(var + 1e-5f);
    }
    __syncthreads();
    float mean = mv[0], rstd = mv[1];
    out[base+tid]     = f2bf((v0-mean)*rstd*g[tid]     + beta[tid]);
    out[base+tid+256] = f2bf((v1-mean)*rstd*g[tid+256] + beta[tid+256]);
    out[base+tid+512] = f2bf((v2-mean)*rstd*g[tid+512] + beta[tid+512]);
}

// bf16 MFMA GEMM (m97 structure): C[M,N] = A[M,K] @ Bt[N,K]^T + bias.
template<int GELU, int OUTBF>
__global__ __launch_bounds__(256) void k_gemm_bf16(const unsigned short* __restrict__ A,
                                                   const unsigned short* __restrict__ Bt,
                                                   const float* __restrict__ bias,
                                                   void* __restrict__ Cv,
                                                   int M, int N, int K) {
    __shared__ unsigned short As[128*32];
    __shared__ unsigned short Bs[128*32];
    const int tid = threadIdx.x;
    const int w = tid >> 6;          // wave 0..3
    const int l = tid & 63;
    const int wm = w >> 1, wn = w & 1;
    const int m0 = blockIdx.y * 128, n0 = blockIdx.x * 128;
    const int lr = l >> 2;           // 0..15
    const int lk = (l & 3) * 8;      // k offset (elements)

    f32x4 acc[4][4] = {};

    for (int k0 = 0; k0 < K; k0 += 32) {
        __syncthreads();
        #pragma unroll
        for (int i = 0; i < 2; ++i) {
            int seg = i*4 + w;
            const unsigned short* ga = A  + (size_t)(m0 + seg*16 + lr)*K + k0 + lk;
            const unsigned short* gb = Bt + (size_t)(n0 + seg*16 + lr)*K + k0 + lk;
            __builtin_amdgcn_global_load_lds((gptr_t)ga, (lptr_t)(As + seg*512), 16, 0, 0);
            __builtin_amdgcn_global_load_lds((gptr_t)gb, (lptr_t)(Bs + seg*512), 16, 0, 0);
        }
        __syncthreads();
        bf16x8 a[4], b[4];
        #pragma unroll
        for (int mi = 0; mi < 4; ++mi)
            a[mi] = *(const bf16x8*)&As[(wm*64 + mi*16 + (l & 15))*32 + (l >> 4)*8];
        #pragma unroll
        for (int ni = 0; ni < 4; ++ni)
            b[ni] = *(const bf16x8*)&Bs[(wn*64 + ni*16 + (l & 15))*32 + (l >> 4)*8];
        #pragma unroll
        for (int mi = 0; mi < 4; ++mi)
            #pragma unroll
            for (int ni = 0; ni < 4; ++ni)
                acc[mi][ni] = __builtin_amdgcn_mfma_f32_16x16x32_bf16(a[mi], b[ni], acc[mi][ni], 0, 0, 0);
    }

    float* Cf = (float*)Cv;
    unsigned short* Cb = (unsigned short*)Cv;
    const int rbase = m0 + wm*64 + (l >> 4)*4;
    const int cbase = n0 + wn*64 + (l & 15);
    #pragma unroll
    for (int ni = 0; ni < 4; ++ni) {
        int col = cbase + ni*16;
        float bv = bias[col];
        #pragma unroll
        for (int mi = 0; mi < 4; ++mi) {
            #pragma unroll
            for (int r = 0; r < 4; ++r) {
                int row = rbase + mi*16 + r;
                float v = acc[mi][ni][r] + bv;
                if (GELU) v = gelu_new(v);
                if (OUTBF) Cb[(size_t)row*N + col] = f2bf(v);
                else       Cf[(size_t)row*N + col] = v;
            }
        }
    }
}

// ---------------- MFMA flash attention ----------------
// Block: 128 q rows x one (b,h). 4 waves, 32 q each (2 m-tiles of 16).
// KV tiles of 64. bf16 in (qkvb/ckvb), f32 softmax/accum, bf16 out.
// LDS tiles 16B-chunk XOR-swizzled by row&7 (G4). K staged via global_load_lds
// with pre-swizzled per-lane SOURCE (m173); V staged transposed (Vt[d][kv]).
__global__ __launch_bounds__(256) void k_attn_mfma(const unsigned short* __restrict__ qkvb,
                                                   const unsigned short* __restrict__ ckvb,
                                                   unsigned short* __restrict__ attnob) {
    const int bh = blockIdx.y;
    const int b = bh / NH, hh = bh % NH;
    const int tid = threadIdx.x;
    const int w = tid >> 6;
    const int l = tid & 63;
    const int lg = l >> 4;       // 0..3
    const int ll = l & 15;

    const int q0 = blockIdx.x * 128;
    const int qw = q0 + w*32;

    __shared__ unsigned short Ks[64*64];      // [key][dh], chunk-swz by key&7
    __shared__ unsigned short Vt[64*64];      // [d][kv],  chunk-swz by d&7
    __shared__ unsigned short Ps[4][32*64];   // per-wave [q][kv], chunk-swz by q&7

    // Q fragments: lane holds Q[q=ll][dh = kc*32 + lg*8 .. +8]
    bf16x8 qf[2][2];
    #pragma unroll
    for (int qt = 0; qt < 2; ++qt) {
        int q = qw + qt*16 + ll;
        int qc = min(q, ND-1);
        const unsigned short* qrow = qkvb + (size_t)(b*ND + qc)*2304 + hh*64;
        #pragma unroll
        for (int kc = 0; kc < 2; ++kc)
            qf[qt][kc] = *(const bf16x8*)(qrow + kc*32 + lg*8);
    }

    f32x4 o_acc[2][4] = {};
    float mrow[2][4], lrow[2][4];
    #pragma unroll
    for (int qt = 0; qt < 2; ++qt)
        #pragma unroll
        for (int i = 0; i < 4; ++i) { mrow[qt][i] = -1e30f; lrow[qt][i] = 0.f; }

    const int qmax_blk = min(q0 + 127, ND-1);
    const int ntiles = (qmax_blk + SCX)/64 + 1;
    const int qmax_wave = qw + 31;

    for (int kt = 0; kt < ntiles; ++kt) {
        __syncthreads();   // previous tile's LDS reads done
        // ---- stage K: global_load_lds, pre-swizzled source (2 instrs/wave)
        #pragma unroll
        for (int it = 0; it < 2; ++it) {
            int slot = w*128 + it*64 + l;         // 0..511 linear LDS 16B slots
            int key  = slot >> 3;
            int ch   = (slot & 7) ^ (key & 7);    // logical dh-chunk stored here
            int kg   = min(kt*64 + key, NS-1);
            const unsigned short* src;
            if (kg < SCX) src = ckvb + (size_t)(b*SCX + kg)*1536 + hh*64 + ch*8;
            else          src = qkvb + (size_t)(b*ND + kg - SCX)*2304 + 768 + hh*64 + ch*8;
            __builtin_amdgcn_global_load_lds((gptr_t)src, (lptr_t)(Ks + (size_t)slot*8), 16, 0, 0);
        }
        // ---- stage V transposed: thread = (kv pair, d-chunk of 8)
        {
            int kp  = tid >> 3;                   // 0..31
            int dch = tid & 7;                    // 0..7
            int kv0 = kp*2;
            int kg0 = min(kt*64 + kv0,     NS-1);
            int kg1 = min(kt*64 + kv0 + 1, NS-1);
            const unsigned short* s0 = (kg0 < SCX)
                ? ckvb + (size_t)(b*SCX + kg0)*1536 + 768 + hh*64 + dch*8
                : qkvb + (size_t)(b*ND + kg0 - SCX)*2304 + 1536 + hh*64 + dch*8;
            const unsigned short* s1 = (kg1 < SCX)
                ? ckvb + (size_t)(b*SCX + kg1)*1536 + 768 + hh*64 + dch*8
                : qkvb + (size_t)(b*ND + kg1 - SCX)*2304 + 1536 + hh*64 + dch*8;
            union { uint4 u; unsigned short s[8]; } r0, r1;
            r0.u = *(const uint4*)s0;
            r1.u = *(const uint4*)s1;
            #pragma unroll
            for (int i = 0; i < 8; ++i) {
                int d = dch*8 + i;
                unsigned val = (unsigned)r0.s[i] | ((unsigned)r1.s[i] << 16);
                *(unsigned*)((char*)Vt + d*128 + (((kv0>>3) ^ (d&7))*16) + ((kv0&7)*2)) = val;
            }
        }
        __syncthreads();   // drains vmcnt (global_load_lds) + lgkm (ds writes)

        if (kt*64 > qmax_wave + SCX) continue;   // wave-uniform: fully masked

        // ---- S = Q K^T
        bf16x8 kf[4][2];
        #pragma unroll
        for (int c = 0; c < 4; ++c) {
            int key = c*16 + ll;
            #pragma unroll
            for (int kc = 0; kc < 2; ++kc)
                kf[c][kc] = *(const bf16x8*)((char*)Ks + key*128 + (((kc*4 + lg) ^ (key&7))*16));
        }
        f32x4 s_acc[2][4];
        #pragma unroll
        for (int qt = 0; qt < 2; ++qt)
            #pragma unroll
            for (int c = 0; c < 4; ++c) {
                f32x4 z = {0.f, 0.f, 0.f, 0.f};
                z = __builtin_amdgcn_mfma_f32_16x16x32_bf16(qf[qt][0], kf[c][0], z, 0, 0, 0);
                s_acc[qt][c] = __builtin_amdgcn_mfma_f32_16x16x32_bf16(qf[qt][1], kf[c][1], z, 0, 0, 0);
            }

        // ---- mask (only boundary tiles)
        const int kbase = kt*64;
        if (kbase + 63 > qw + SCX) {
            #pragma unroll
            for (int qt = 0; qt < 2; ++qt)
                #pragma unroll
                for (int c = 0; c < 4; ++c) {
                    int key = kbase + c*16 + ll;
                    #pragma unroll
                    for (int i = 0; i < 4; ++i) {
                        int q = qw + qt*16 + lg*4 + i;
                        if (key > q + SCX) s_acc[qt][c][i] = -1e30f;
                    }
                }
        }

        // ---- online softmax (row = (lg*4+i) within 16-row tile; 16-lane row groups)
        #pragma unroll
        for (int qt = 0; qt < 2; ++qt) {
            float tmax[4];
            #pragma unroll
            for (int i = 0; i < 4; ++i) {
                float tm = fmaxf(fmaxf(s_acc[qt][0][i], s_acc[qt][1][i]),
                                 fmaxf(s_acc[qt][2][i], s_acc[qt][3][i]));
                #pragma unroll
                for (int o = 1; o < 16; o <<= 1) tm = fmaxf(tm, __shfl_xor(tm, o));
                tmax[i] = tm;
            }
            #pragma unroll
            for (int i = 0; i < 4; ++i) {
                float mnew = fmaxf(mrow[qt][i], tmax[i]*0.125f);
                float fs = __expf(mrow[qt][i] - mnew);
                mrow[qt][i] = mnew;
                lrow[qt][i] *= fs;
                #pragma unroll
                for (int dc = 0; dc < 4; ++dc) o_acc[qt][dc][i] *= fs;
            }
            float psum[4] = {0.f, 0.f, 0.f, 0.f};
            #pragma unroll
            for (int c = 0; c < 4; ++c) {
                int kv = c*16 + ll;
                #pragma unroll
                for (int i = 0; i < 4; ++i) {
                    float p = __expf(fmaf(s_acc[qt][c][i], 0.125f, -mrow[qt][i]));
                    psum[i] += p;
                    int q = qt*16 + lg*4 + i;       // local 0..31
                    union { float f; unsigned u; } cv; cv.f = p;
                    *(unsigned short*)((char*)Ps[w] + q*128 + (((kv>>3) ^ (q&7))*16) + ((kv&7)*2))
                        = (unsigned short)((cv.u + 0x8000u) >> 16);
                }
            }
            #pragma unroll
            for (int i = 0; i < 4; ++i) {
                float s = psum[i];
                #pragma unroll
                for (int o = 1; o < 16; o <<= 1) s += __shfl_xor(s, o);
                lrow[qt][i] += s;
            }
        }

        // ---- PV: O += P @ V   (A from Ps, B from Vt; same wave, compiler waits)
        #pragma unroll
        for (int kc = 0; kc < 2; ++kc) {
            bf16x8 pf[2], vf;
            #pragma unroll
            for (int qt = 0; qt < 2; ++qt) {
                int q = qt*16 + ll;
                pf[qt] = *(const bf16x8*)((char*)Ps[w] + q*128 + (((kc*4 + lg) ^ (q&7))*16));
            }
            #pragma unroll
            for (int dc = 0; dc < 4; ++dc) {
                int d = dc*16 + ll;
                vf = *(const bf16x8*)((char*)Vt + d*128 + (((kc*4 + lg) ^ (d&7))*16));
                #pragma unroll
                for (int qt = 0; qt < 2; ++qt)
                    o_acc[qt][dc] = __builtin_amdgcn_mfma_f32_16x16x32_bf16(pf[qt], vf, o_acc[qt][dc], 0, 0, 0);
            }
        }
    }

    // ---- epilogue: O / lsum -> bf16
    #pragma unroll
    for (int qt = 0; qt < 2; ++qt) {
        #pragma unroll
        for (int i = 0; i < 4; ++i) {
            int q = qw + qt*16 + lg*4 + i;
            if (q >= ND) continue;
            float inv = 1.f / lrow[qt][i];
            unsigned short* orow = attnob + (size_t)(b*ND + q)*768 + hh*64;
            #pragma unroll
            for (int dc = 0; dc < 4; ++dc)
                orow[dc*16 + ll] = f2bf(o_acc[qt][dc][i] * inv);
        }
    }
}

// out[b,t,:] = h[b, t+1, :] + mproj[b, t+1, :]   (drop sos row)
__global__ void k_final(const float* __restrict__ h, const float* __restrict__ mp,
                        float* __restrict__ out) {
    int idx = blockIdx.x*blockDim.x + threadIdx.x;
    const int total = NB*SQ*192;
    if (idx >= total) return;
    int r = idx/192, c4 = idx%192;
    int b = r/SQ, t = r%SQ;
    size_t hr = (size_t)(b*ND + t + 1)*192 + c4;
    float4 hv = ((const float4*)h)[hr];
    float4 mv = ((const float4*)mp)[hr];
    ((float4*)out)[idx] = make_float4(hv.x+mv.x, hv.y+mv.y, hv.z+mv.z, hv.w+mv.w);
}

extern "C" void kernel_launch(void* const* d_in, const int* in_sizes, int n_in,
                              void* d_out, int out_size, void* d_ws, size_t ws_size,
                              hipStream_t stream) {
    const float* x     = (const float*)d_in[0];
    const float* ctx   = (const float*)d_in[1];
    const float* sos   = (const float*)d_in[2];
    const float* ln1g  = (const float*)d_in[3];
    const float* ln1b  = (const float*)d_in[4];
    const float* Wat   = (const float*)d_in[5];
    const float* bat   = (const float*)d_in[6];
    const float* Wref  = (const float*)d_in[7];
    const float* bref  = (const float*)d_in[8];
    const float* Wpj   = (const float*)d_in[9];
    const float* bpj   = (const float*)d_in[10];
    const float* ln2g  = (const float*)d_in[11];
    const float* ln2b  = (const float*)d_in[12];
    const float* Wfc   = (const float*)d_in[13];
    const float* bfc   = (const float*)d_in[14];
    const float* Wmp   = (const float*)d_in[15];
    const float* bmp   = (const float*)d_in[16];
    float* out = (float*)d_out;

    char* p = (char*)d_ws;
    float* h      = (float*)p;  p += (size_t)TP*768*4;
    float* aproj  = (float*)p;  p += (size_t)TP*768*4;   // proj out, reused for mproj out
    unsigned short* qkvb   = (unsigned short*)p;  p += (size_t)TP*2304*2;
    unsigned short* ckvb   = (unsigned short*)p;  p += (size_t)TC*1536*2;
    unsigned short* hlb    = (unsigned short*)p;  p += (size_t)TP*768*2;
    unsigned short* attnob = (unsigned short*)p;  p += (size_t)TP*768*2;
    unsigned short* mfcb   = (unsigned short*)p;  p += (size_t)TP*3072*2;
    unsigned short* ctxb   = (unsigned short*)p;  p += (size_t)TC*768*2;
    unsigned short* WatT   = (unsigned short*)p;  p += (size_t)2304*768*2;
    unsigned short* WrefT  = (unsigned short*)p;  p += (size_t)1536*768*2;
    unsigned short* WpjT   = (unsigned short*)p;  p += (size_t)768*768*2;
    unsigned short* WfcT   = (unsigned short*)p;  p += (size_t)3072*768*2;
    unsigned short* WmpT   = (unsigned short*)p;  p += (size_t)768*3072*2;

    // Weight transposes f32 [K][N] -> bf16 [N][K]
    k_transpose_bf<<<dim3(2304/32, 768/32),  dim3(256), 0, stream>>>(Wat, WatT, 768, 2304);
    k_transpose_bf<<<dim3(1536/32, 768/32),  dim3(256), 0, stream>>>(Wref, WrefT, 768, 1536);
    k_transpose_bf<<<dim3(768/32,  768/32),  dim3(256), 0, stream>>>(Wpj, WpjT, 768, 768);
    k_transpose_bf<<<dim3(3072/32, 768/32),  dim3(256), 0, stream>>>(Wfc, WfcT, 768, 3072);
    k_transpose_bf<<<dim3(768/32,  3072/32), dim3(256), 0, stream>>>(Wmp, WmpT, 3072, 768);

    k_build_h<<<dim3((TT*192 + 255)/256), dim3(256), 0, stream>>>(x, sos, h);
    k_cvt_bf<<<dim3((TC*768/8 + 255)/256), dim3(256), 0, stream>>>(ctx, ctxb, TC*768/8);

    k_ln<<<dim3(TP), dim3(256), 0, stream>>>(h, nullptr, ln1g, ln1b, hlb, nullptr, TT);
    k_gemm_bf16<0,1><<<dim3(2304/128, TP/128), dim3(256), 0, stream>>>(hlb, WatT, bat, qkvb, TP, 2304, 768);
    k_gemm_bf16<0,1><<<dim3(1536/128, TC/128), dim3(256), 0, stream>>>(ctxb, WrefT, bref, ckvb, TC, 1536, 768);
    k_attn_mfma<<<dim3(9, NB*NH), dim3(256), 0, stream>>>(qkvb, ckvb, attnob);
    k_gemm_bf16<0,0><<<dim3(768/128, TP/128), dim3(256), 0, stream>>>(attnob, WpjT, bpj, aproj, TP, 768, 768);
    k_ln<<<dim3(TP), dim3(256), 0, stream>>>(h, aproj, ln2g, ln2b, hlb, h, TT);
    k_gemm_bf16<1,1><<<dim3(3072/128, TP/128), dim3(256), 0, stream>>>(hlb, WfcT, bfc, mfcb, TP, 3072, 768);
    k_gemm_bf16<0,0><<<dim3(768/128, TP/128), dim3(256), 0, stream>>>(mfcb, WmpT, bmp, aproj, TP, 768, 3072);
    k_final<<<dim3((NB*SQ*192 + 255)/256), dim3(256), 0, stream>>>(h, aproj, out);
}

// Round 5
// 282.873 us; speedup vs baseline: 3.3517x; 1.2804x over previous
//
#include <hip/hip_runtime.h>
#include <math.h>

// Problem constants
#define D0 768
#define NH 12
#define DHD 64
#define NB 2
#define SQ 1024
#define SCX 256
#define ND 1025            // SQ + 1 (sos prepended)
#define NS 1281            // SCX + ND
#define TT (NB*ND)         // 2050 total h rows
#define TP 2176            // padded rows (34*64)
#define TC (NB*SCX)        // 512 context rows

typedef __attribute__((ext_vector_type(8))) short bf16x8;   // 8 bf16 in 4 VGPRs
typedef __attribute__((ext_vector_type(4))) float f32x4;

typedef const __attribute__((address_space(1))) unsigned int* gptr_t;
typedef __attribute__((address_space(3))) unsigned int* lptr_t;

__device__ __forceinline__ unsigned short f2bf(float f) {
    union { float f; unsigned u; } v; v.f = f;
    unsigned r = v.u + 0x7FFFu + ((v.u >> 16) & 1u);
    return (unsigned short)(r >> 16);
}

__device__ __forceinline__ float gelu_new(float x) {
    float x3 = x*x*x;
    float u = 0.7978845608028654f*(x + 0.044715f*x3);
    return 0.5f*x*(1.f + tanhf(u));
}

// ---------------- fused prep: build_h + ctx->bf16 + 5 weight transposes ----------------
struct PrepArgs {
    const float* x; const float* sos; float* h;
    const float* ctx; unsigned short* ctxb;
    const float* W[5]; unsigned short* Wt[5];
    int K[5], N[5], nblk[5];
};

#define NBH 1538           // ceil(TT*192/256)
#define NCVT 192           // TC*768/8/256

__global__ __launch_bounds__(256) void k_prep(PrepArgs a) {
    __shared__ float t[32][33];
    const int tid = threadIdx.x;
    int bid = blockIdx.x;
    if (bid < NBH) {                       // h = concat(sos, x)
        int idx = bid*256 + tid;
        if (idx < TT*192) {
            int r = idx/192, c4 = idx%192;
            int b = r/ND, tt = r%ND;
            float4 v;
            if (tt == 0) v = ((const float4*)a.sos)[c4];
            else         v = ((const float4*)a.x)[(size_t)(b*SQ + tt - 1)*192 + c4];
            ((float4*)a.h)[(size_t)r*192 + c4] = v;
        }
        return;
    }
    bid -= NBH;
    if (bid < NCVT) {                      // ctx f32 -> bf16
        int i = bid*256 + tid;
        float4 p = ((const float4*)a.ctx)[i*2];
        float4 q = ((const float4*)a.ctx)[i*2+1];
        uint4 o;
        o.x = (unsigned)f2bf(p.x) | ((unsigned)f2bf(p.y) << 16);
        o.y = (unsigned)f2bf(p.z) | ((unsigned)f2bf(p.w) << 16);
        o.z = (unsigned)f2bf(q.x) | ((unsigned)f2bf(q.y) << 16);
        o.w = (unsigned)f2bf(q.z) | ((unsigned)f2bf(q.w) << 16);
        ((uint4*)a.ctxb)[i] = o;
        return;
    }
    bid -= NCVT;
    #pragma unroll
    for (int wi = 0; wi < 5; ++wi) {
        if (bid < a.nblk[wi]) {            // W[K][N] f32 -> Wt[N][K] bf16
            const float* W = a.W[wi];
            unsigned short* Wt = a.Wt[wi];
            const int K = a.K[wi], N = a.N[wi];
            const int nbx = N >> 5;
            const int n0 = (bid % nbx)*32, k0 = (bid / nbx)*32;
            const int r = tid >> 3, c4 = (tid & 7)*4;
            float4 v = *(const float4*)&W[(size_t)(k0+r)*N + n0 + c4];
            t[r][c4+0]=v.x; t[r][c4+1]=v.y; t[r][c4+2]=v.z; t[r][c4+3]=v.w;
            __syncthreads();
            ushort4 o;
            o.x = f2bf(t[c4+0][r]); o.y = f2bf(t[c4+1][r]);
            o.z = f2bf(t[c4+2][r]); o.w = f2bf(t[c4+3][r]);
            *(ushort4*)&Wt[(size_t)(n0+r)*K + k0 + c4] = o;
            return;
        }
        bid -= a.nblk[wi];
    }
}

// LayerNorm over 768, bf16 output. Optional fused residual add (in += add -> resid).
__global__ __launch_bounds__(256) void k_ln(const float* __restrict__ in,
                                            const float* __restrict__ add,
                                            const float* __restrict__ g,
                                            const float* __restrict__ beta,
                                            unsigned short* __restrict__ out,
                                            float* __restrict__ resid,
                                            int nvalid) {
    int r = blockIdx.x;
    int tid = threadIdx.x;
    const size_t base = (size_t)r*D0;
    if (r >= nvalid) {
        out[base+tid] = 0; out[base+tid+256] = 0; out[base+tid+512] = 0;
        return;
    }
    float v0 = in[base+tid], v1 = in[base+tid+256], v2 = in[base+tid+512];
    if (add) {
        v0 += add[base+tid]; v1 += add[base+tid+256]; v2 += add[base+tid+512];
        resid[base+tid] = v0; resid[base+tid+256] = v1; resid[base+tid+512] = v2;
    }
    float s = v0+v1+v2;
    float ss = v0*v0 + v1*v1 + v2*v2;
    #pragma unroll
    for (int o = 32; o >= 1; o >>= 1) {
        s  += __shfl_down(s, o);
        ss += __shfl_down(ss, o);
    }
    __shared__ float red[8];
    __shared__ float mv[2];
    int w = tid >> 6;
    if ((tid & 63) == 0) { red[w] = s; red[4+w] = ss; }
    __syncthreads();
    if (tid == 0) {
        float S1 = red[0]+red[1]+red[2]+red[3];
        float S2 = red[4]+red[5]+red[6]+red[7];
        float mean = S1 * (1.f/D0);
        float var  = S2 * (1.f/D0) - mean*mean;
        mv[0] = mean; mv[1] = rsqrtf(var + 1e-5f);
    }
    __syncthreads();
    float mean = mv[0], rstd = mv[1];
    out[base+tid]     = f2bf((v0-mean)*rstd*g[tid]     + beta[tid]);
    out[base+tid+256] = f2bf((v1-mean)*rstd*g[tid+256] + beta[tid+256]);
    out[base+tid+512] = f2bf((v2-mean)*rstd*g[tid+512] + beta[tid+512]);
}

// bf16 MFMA GEMM, 64x64 tile / BK=64 (occupancy-oriented for skinny N):
// C[M,N] = A[M,K] @ Bt[N,K]^T + bias. 4 waves 2x2, each 32x32 out (2x2 frags).
// LDS rows are 128B -> chunk-XOR swizzle by row&7, applied on BOTH the
// global_load_lds SOURCE address and the ds_read (rule #21 involution).
template<int GELU, int OUTBF>
__global__ __launch_bounds__(256) void k_gemm64(const unsigned short* __restrict__ A,
                                                const unsigned short* __restrict__ Bt,
                                                const float* __restrict__ bias,
                                                void* __restrict__ Cv,
                                                int M, int N, int K) {
    __shared__ unsigned short As[64*64];
    __shared__ unsigned short Bs[64*64];
    const int tid = threadIdx.x;
    const int w = tid >> 6;          // wave 0..3
    const int l = tid & 63;
    const int wm = w >> 1, wn = w & 1;
    const int m0 = blockIdx.y * 64, n0 = blockIdx.x * 64;

    f32x4 acc[2][2] = {};

    for (int k0 = 0; k0 < K; k0 += 64) {
        __syncthreads();
        #pragma unroll
        for (int i = 0; i < 2; ++i) {
            int s = i*256 + tid;             // 16B slot 0..511
            int row = s >> 3;
            int ch  = (s & 7) ^ (row & 7);   // logical k-chunk stored at this slot
            const unsigned short* ga = A  + (size_t)(m0 + row)*K + k0 + ch*8;
            const unsigned short* gb = Bt + (size_t)(n0 + row)*K + k0 + ch*8;
            lptr_t la = (lptr_t)(As + (i*256 + w*64)*8);   // wave-uniform base
            lptr_t lb = (lptr_t)(Bs + (i*256 + w*64)*8);
            __builtin_amdgcn_global_load_lds((gptr_t)ga, la, 16, 0, 0);
            __builtin_amdgcn_global_load_lds((gptr_t)gb, lb, 16, 0, 0);
        }
        __syncthreads();
        #pragma unroll
        for (int kc = 0; kc < 2; ++kc) {
            const int kchunk = kc*4 + (l >> 4);
            bf16x8 a[2], b[2];
            #pragma unroll
            for (int mi = 0; mi < 2; ++mi) {
                int row = wm*32 + mi*16 + (l & 15);
                a[mi] = *(const bf16x8*)&As[row*64 + ((kchunk ^ (row & 7))*8)];
            }
            #pragma unroll
            for (int ni = 0; ni < 2; ++ni) {
                int row = wn*32 + ni*16 + (l & 15);
                b[ni] = *(const bf16x8*)&Bs[row*64 + ((kchunk ^ (row & 7))*8)];
            }
            #pragma unroll
            for (int mi = 0; mi < 2; ++mi)
                #pragma unroll
                for (int ni = 0; ni < 2; ++ni)
                    acc[mi][ni] = __builtin_amdgcn_mfma_f32_16x16x32_bf16(a[mi], b[ni], acc[mi][ni], 0, 0, 0);
        }
    }

    // Epilogue. C/D layout (HW-verified): col = lane&15, row = (lane>>4)*4 + reg.
    float* Cf = (float*)Cv;
    unsigned short* Cb = (unsigned short*)Cv;
    const int rbase = m0 + wm*32 + (l >> 4)*4;
    const int cbase = n0 + wn*32 + (l & 15);
    #pragma unroll
    for (int ni = 0; ni < 2; ++ni) {
        int col = cbase + ni*16;
        float bv = bias[col];
        #pragma unroll
        for (int mi = 0; mi < 2; ++mi) {
            #pragma unroll
            for (int r = 0; r < 4; ++r) {
                int row = rbase + mi*16 + r;
                float v = acc[mi][ni][r] + bv;
                if (GELU) v = gelu_new(v);
                if (OUTBF) Cb[(size_t)row*N + col] = f2bf(v);
                else       Cf[(size_t)row*N + col] = v;
            }
        }
    }
}

// ---------------- MFMA flash attention ----------------
// Block: 128 q rows x one (b,h). 4 waves, 32 q each (2 m-tiles of 16).
__global__ __launch_bounds__(256) void k_attn_mfma(const unsigned short* __restrict__ qkvb,
                                                   const unsigned short* __restrict__ ckvb,
                                                   unsigned short* __restrict__ attnob) {
    const int bh = blockIdx.y;
    const int b = bh / NH, hh = bh % NH;
    const int tid = threadIdx.x;
    const int w = tid >> 6;
    const int l = tid & 63;
    const int lg = l >> 4;       // 0..3
    const int ll = l & 15;

    const int q0 = blockIdx.x * 128;
    const int qw = q0 + w*32;

    __shared__ unsigned short Ks[64*64];      // [key][dh], chunk-swz by key&7
    __shared__ unsigned short Vt[64*64];      // [d][kv],  chunk-swz by d&7
    __shared__ unsigned short Ps[4][32*64];   // per-wave [q][kv], chunk-swz by q&7

    bf16x8 qf[2][2];
    #pragma unroll
    for (int qt = 0; qt < 2; ++qt) {
        int q = qw + qt*16 + ll;
        int qc = min(q, ND-1);
        const unsigned short* qrow = qkvb + (size_t)(b*ND + qc)*2304 + hh*64;
        #pragma unroll
        for (int kc = 0; kc < 2; ++kc)
            qf[qt][kc] = *(const bf16x8*)(qrow + kc*32 + lg*8);
    }

    f32x4 o_acc[2][4] = {};
    float mrow[2][4], lrow[2][4];
    #pragma unroll
    for (int qt = 0; qt < 2; ++qt)
        #pragma unroll
        for (int i = 0; i < 4; ++i) { mrow[qt][i] = -1e30f; lrow[qt][i] = 0.f; }

    const int qmax_blk = min(q0 + 127, ND-1);
    const int ntiles = (qmax_blk + SCX)/64 + 1;
    const int qmax_wave = qw + 31;

    for (int kt = 0; kt < ntiles; ++kt) {
        __syncthreads();
        #pragma unroll
        for (int it = 0; it < 2; ++it) {
            int slot = w*128 + it*64 + l;
            int key  = slot >> 3;
            int ch   = (slot & 7) ^ (key & 7);
            int kg   = min(kt*64 + key, NS-1);
            const unsigned short* src;
            if (kg < SCX) src = ckvb + (size_t)(b*SCX + kg)*1536 + hh*64 + ch*8;
            else          src = qkvb + (size_t)(b*ND + kg - SCX)*2304 + 768 + hh*64 + ch*8;
            __builtin_amdgcn_global_load_lds((gptr_t)src, (lptr_t)(Ks + (size_t)(w*128 + it*64)*8), 16, 0, 0);
        }
        {
            int kp  = tid >> 3;
            int dch = tid & 7;
            int kv0 = kp*2;
            int kg0 = min(kt*64 + kv0,     NS-1);
            int kg1 = min(kt*64 + kv0 + 1, NS-1);
            const unsigned short* s0 = (kg0 < SCX)
                ? ckvb + (size_t)(b*SCX + kg0)*1536 + 768 + hh*64 + dch*8
                : qkvb + (size_t)(b*ND + kg0 - SCX)*2304 + 1536 + hh*64 + dch*8;
            const unsigned short* s1 = (kg1 < SCX)
                ? ckvb + (size_t)(b*SCX + kg1)*1536 + 768 + hh*64 + dch*8
                : qkvb + (size_t)(b*ND + kg1 - SCX)*2304 + 1536 + hh*64 + dch*8;
            union { uint4 u; unsigned short s[8]; } r0, r1;
            r0.u = *(const uint4*)s0;
            r1.u = *(const uint4*)s1;
            #pragma unroll
            for (int i = 0; i < 8; ++i) {
                int d = dch*8 + i;
                unsigned val = (unsigned)r0.s[i] | ((unsigned)r1.s[i] << 16);
                *(unsigned*)((char*)Vt + d*128 + (((kv0>>3) ^ (d&7))*16) + ((kv0&7)*2)) = val;
            }
        }
        __syncthreads();

        if (kt*64 > qmax_wave + SCX) continue;

        bf16x8 kf[4][2];
        #pragma unroll
        for (int c = 0; c < 4; ++c) {
            int key = c*16 + ll;
            #pragma unroll
            for (int kc = 0; kc < 2; ++kc)
                kf[c][kc] = *(const bf16x8*)((char*)Ks + key*128 + (((kc*4 + lg) ^ (key&7))*16));
        }
        f32x4 s_acc[2][4];
        #pragma unroll
        for (int qt = 0; qt < 2; ++qt)
            #pragma unroll
            for (int c = 0; c < 4; ++c) {
                f32x4 z = {0.f, 0.f, 0.f, 0.f};
                z = __builtin_amdgcn_mfma_f32_16x16x32_bf16(qf[qt][0], kf[c][0], z, 0, 0, 0);
                s_acc[qt][c] = __builtin_amdgcn_mfma_f32_16x16x32_bf16(qf[qt][1], kf[c][1], z, 0, 0, 0);
            }

        const int kbase = kt*64;
        if (kbase + 63 > qw + SCX) {
            #pragma unroll
            for (int qt = 0; qt < 2; ++qt)
                #pragma unroll
                for (int c = 0; c < 4; ++c) {
                    int key = kbase + c*16 + ll;
                    #pragma unroll
                    for (int i = 0; i < 4; ++i) {
                        int q = qw + qt*16 + lg*4 + i;
                        if (key > q + SCX) s_acc[qt][c][i] = -1e30f;
                    }
                }
        }

        #pragma unroll
        for (int qt = 0; qt < 2; ++qt) {
            float tmax[4];
            #pragma unroll
            for (int i = 0; i < 4; ++i) {
                float tm = fmaxf(fmaxf(s_acc[qt][0][i], s_acc[qt][1][i]),
                                 fmaxf(s_acc[qt][2][i], s_acc[qt][3][i]));
                #pragma unroll
                for (int o = 1; o < 16; o <<= 1) tm = fmaxf(tm, __shfl_xor(tm, o));
                tmax[i] = tm;
            }
            #pragma unroll
            for (int i = 0; i < 4; ++i) {
                float mnew = fmaxf(mrow[qt][i], tmax[i]*0.125f);
                float fs = __expf(mrow[qt][i] - mnew);
                mrow[qt][i] = mnew;
                lrow[qt][i] *= fs;
                #pragma unroll
                for (int dc = 0; dc < 4; ++dc) o_acc[qt][dc][i] *= fs;
            }
            float psum[4] = {0.f, 0.f, 0.f, 0.f};
            #pragma unroll
            for (int c = 0; c < 4; ++c) {
                int kv = c*16 + ll;
                #pragma unroll
                for (int i = 0; i < 4; ++i) {
                    float p = __expf(fmaf(s_acc[qt][c][i], 0.125f, -mrow[qt][i]));
                    psum[i] += p;
                    int q = qt*16 + lg*4 + i;
                    union { float f; unsigned u; } cv; cv.f = p;
                    *(unsigned short*)((char*)Ps[w] + q*128 + (((kv>>3) ^ (q&7))*16) + ((kv&7)*2))
                        = (unsigned short)((cv.u + 0x8000u) >> 16);
                }
            }
            #pragma unroll
            for (int i = 0; i < 4; ++i) {
                float s = psum[i];
                #pragma unroll
                for (int o = 1; o < 16; o <<= 1) s += __shfl_xor(s, o);
                lrow[qt][i] += s;
            }
        }

        #pragma unroll
        for (int kc = 0; kc < 2; ++kc) {
            bf16x8 pf[2], vf;
            #pragma unroll
            for (int qt = 0; qt < 2; ++qt) {
                int q = qt*16 + ll;
                pf[qt] = *(const bf16x8*)((char*)Ps[w] + q*128 + (((kc*4 + lg) ^ (q&7))*16));
            }
            #pragma unroll
            for (int dc = 0; dc < 4; ++dc) {
                int d = dc*16 + ll;
                vf = *(const bf16x8*)((char*)Vt + d*128 + (((kc*4 + lg) ^ (d&7))*16));
                #pragma unroll
                for (int qt = 0; qt < 2; ++qt)
                    o_acc[qt][dc] = __builtin_amdgcn_mfma_f32_16x16x32_bf16(pf[qt], vf, o_acc[qt][dc], 0, 0, 0);
            }
        }
    }

    #pragma unroll
    for (int qt = 0; qt < 2; ++qt) {
        #pragma unroll
        for (int i = 0; i < 4; ++i) {
            int q = qw + qt*16 + lg*4 + i;
            if (q >= ND) continue;
            float inv = 1.f / lrow[qt][i];
            unsigned short* orow = attnob + (size_t)(b*ND + q)*768 + hh*64;
            #pragma unroll
            for (int dc = 0; dc < 4; ++dc)
                orow[dc*16 + ll] = f2bf(o_acc[qt][dc][i] * inv);
        }
    }
}

// out[b,t,:] = h[b, t+1, :] + mproj[b, t+1, :]   (drop sos row)
__global__ void k_final(const float* __restrict__ h, const float* __restrict__ mp,
                        float* __restrict__ out) {
    int idx = blockIdx.x*blockDim.x + threadIdx.x;
    const int total = NB*SQ*192;
    if (idx >= total) return;
    int r = idx/192, c4 = idx%192;
    int b = r/SQ, t = r%SQ;
    size_t hr = (size_t)(b*ND + t + 1)*192 + c4;
    float4 hv = ((const float4*)h)[hr];
    float4 mv = ((const float4*)mp)[hr];
    ((float4*)out)[idx] = make_float4(hv.x+mv.x, hv.y+mv.y, hv.z+mv.z, hv.w+mv.w);
}

extern "C" void kernel_launch(void* const* d_in, const int* in_sizes, int n_in,
                              void* d_out, int out_size, void* d_ws, size_t ws_size,
                              hipStream_t stream) {
    const float* x     = (const float*)d_in[0];
    const float* ctx   = (const float*)d_in[1];
    const float* sos   = (const float*)d_in[2];
    const float* ln1g  = (const float*)d_in[3];
    const float* ln1b  = (const float*)d_in[4];
    const float* Wat   = (const float*)d_in[5];
    const float* bat   = (const float*)d_in[6];
    const float* Wref  = (const float*)d_in[7];
    const float* bref  = (const float*)d_in[8];
    const float* Wpj   = (const float*)d_in[9];
    const float* bpj   = (const float*)d_in[10];
    const float* ln2g  = (const float*)d_in[11];
    const float* ln2b  = (const float*)d_in[12];
    const float* Wfc   = (const float*)d_in[13];
    const float* bfc   = (const float*)d_in[14];
    const float* Wmp   = (const float*)d_in[15];
    const float* bmp   = (const float*)d_in[16];
    float* out = (float*)d_out;

    char* p = (char*)d_ws;
    float* h      = (float*)p;  p += (size_t)TP*768*4;
    float* aproj  = (float*)p;  p += (size_t)TP*768*4;
    unsigned short* qkvb   = (unsigned short*)p;  p += (size_t)TP*2304*2;
    unsigned short* ckvb   = (unsigned short*)p;  p += (size_t)TC*1536*2;
    unsigned short* hlb    = (unsigned short*)p;  p += (size_t)TP*768*2;
    unsigned short* attnob = (unsigned short*)p;  p += (size_t)TP*768*2;
    unsigned short* mfcb   = (unsigned short*)p;  p += (size_t)TP*3072*2;
    unsigned short* ctxb   = (unsigned short*)p;  p += (size_t)TC*768*2;
    unsigned short* WatT   = (unsigned short*)p;  p += (size_t)2304*768*2;
    unsigned short* WrefT  = (unsigned short*)p;  p += (size_t)1536*768*2;
    unsigned short* WpjT   = (unsigned short*)p;  p += (size_t)768*768*2;
    unsigned short* WfcT   = (unsigned short*)p;  p += (size_t)3072*768*2;
    unsigned short* WmpT   = (unsigned short*)p;  p += (size_t)768*3072*2;

    PrepArgs pa;
    pa.x = x; pa.sos = sos; pa.h = h; pa.ctx = ctx; pa.ctxb = ctxb;
    pa.W[0]=Wat;  pa.Wt[0]=WatT;  pa.K[0]=768;  pa.N[0]=2304; pa.nblk[0]=(2304/32)*(768/32);
    pa.W[1]=Wref; pa.Wt[1]=WrefT; pa.K[1]=768;  pa.N[1]=1536; pa.nblk[1]=(1536/32)*(768/32);
    pa.W[2]=Wpj;  pa.Wt[2]=WpjT;  pa.K[2]=768;  pa.N[2]=768;  pa.nblk[2]=(768/32)*(768/32);
    pa.W[3]=Wfc;  pa.Wt[3]=WfcT;  pa.K[3]=768;  pa.N[3]=3072; pa.nblk[3]=(3072/32)*(768/32);
    pa.W[4]=Wmp;  pa.Wt[4]=WmpT;  pa.K[4]=3072; pa.N[4]=768;  pa.nblk[4]=(768/32)*(3072/32);
    int nprep = NBH + NCVT + pa.nblk[0]+pa.nblk[1]+pa.nblk[2]+pa.nblk[3]+pa.nblk[4];

    k_prep<<<dim3(nprep), dim3(256), 0, stream>>>(pa);
    k_ln<<<dim3(TP), dim3(256), 0, stream>>>(h, nullptr, ln1g, ln1b, hlb, nullptr, TT);
    k_gemm64<0,1><<<dim3(2304/64, TP/64), dim3(256), 0, stream>>>(hlb, WatT, bat, qkvb, TP, 2304, 768);
    k_gemm64<0,1><<<dim3(1536/64, TC/64), dim3(256), 0, stream>>>(ctxb, WrefT, bref, ckvb, TC, 1536, 768);
    k_attn_mfma<<<dim3(9, NB*NH), dim3(256), 0, stream>>>(qkvb, ckvb, attnob);
    k_gemm64<0,0><<<dim3(768/64, TP/64), dim3(256), 0, stream>>>(attnob, WpjT, bpj, aproj, TP, 768, 768);
    k_ln<<<dim3(TP), dim3(256), 0, stream>>>(h, aproj, ln2g, ln2b, hlb, h, TT);
    k_gemm64<1,1><<<dim3(3072/64, TP/64), dim3(256), 0, stream>>>(hlb, WfcT, bfc, mfcb, TP, 3072, 768);
    k_gemm64<0,0><<<dim3(768/64, TP/64), dim3(256), 0, stream>>>(mfcb, WmpT, bmp, aproj, TP, 768, 3072);
    k_final<<<dim3((NB*SQ*192 + 255)/256), dim3(256), 0, stream>>>(h, aproj, out);
}

// Round 7
// 255.337 us; speedup vs baseline: 3.7132x; 1.1078x over previous
//
#include <hip/hip_runtime.h>
#include <math.h>

// Problem constants
#define D0 768
#define NH 12
#define DHD 64
#define NB 2
#define SQ 1024
#define SCX 256
#define ND 1025            // SQ + 1 (sos prepended)
#define NS 1281            // SCX + ND
#define TT (NB*ND)         // 2050 total h rows
#define TP 2176            // padded rows (34*64)
#define TC (NB*SCX)        // 512 context rows

typedef __attribute__((ext_vector_type(8))) short bf16x8;   // 8 bf16 in 4 VGPRs
typedef __attribute__((ext_vector_type(4))) float f32x4;

typedef const __attribute__((address_space(1))) unsigned int* gptr_t;
typedef __attribute__((address_space(3))) unsigned int* lptr_t;

__device__ __forceinline__ unsigned short f2bf(float f) {
    union { float f; unsigned u; } v; v.f = f;
    unsigned r = v.u + 0x7FFFu + ((v.u >> 16) & 1u);
    return (unsigned short)(r >> 16);
}

__device__ __forceinline__ float gelu_new(float x) {
    float x3 = x*x*x;
    float u = 0.7978845608028654f*(x + 0.044715f*x3);
    return 0.5f*x*(1.f + tanhf(u));
}

// ---------------- fused prep: build_h + ctx->bf16 + 5 weight transposes ----------------
struct PrepArgs {
    const float* x; const float* sos; float* h;
    const float* ctx; unsigned short* ctxb;
    const float* W[5]; unsigned short* Wt[5];
    int K[5], N[5], nblk[5];
};

#define NBH 1538           // ceil(TT*192/256)
#define NCVT 192           // TC*768/8/256

__global__ __launch_bounds__(256) void k_prep(PrepArgs a) {
    __shared__ float t[32][33];
    const int tid = threadIdx.x;
    int bid = blockIdx.x;
    if (bid < NBH) {                       // h = concat(sos, x)
        int idx = bid*256 + tid;
        if (idx < TT*192) {
            int r = idx/192, c4 = idx%192;
            int b = r/ND, tt = r%ND;
            float4 v;
            if (tt == 0) v = ((const float4*)a.sos)[c4];
            else         v = ((const float4*)a.x)[(size_t)(b*SQ + tt - 1)*192 + c4];
            ((float4*)a.h)[(size_t)r*192 + c4] = v;
        }
        return;
    }
    bid -= NBH;
    if (bid < NCVT) {                      // ctx f32 -> bf16
        int i = bid*256 + tid;
        float4 p = ((const float4*)a.ctx)[i*2];
        float4 q = ((const float4*)a.ctx)[i*2+1];
        uint4 o;
        o.x = (unsigned)f2bf(p.x) | ((unsigned)f2bf(p.y) << 16);
        o.y = (unsigned)f2bf(p.z) | ((unsigned)f2bf(p.w) << 16);
        o.z = (unsigned)f2bf(q.x) | ((unsigned)f2bf(q.y) << 16);
        o.w = (unsigned)f2bf(q.z) | ((unsigned)f2bf(q.w) << 16);
        ((uint4*)a.ctxb)[i] = o;
        return;
    }
    bid -= NCVT;
    #pragma unroll
    for (int wi = 0; wi < 5; ++wi) {
        if (bid < a.nblk[wi]) {            // W[K][N] f32 -> Wt[N][K] bf16
            const float* W = a.W[wi];
            unsigned short* Wt = a.Wt[wi];
            const int K = a.K[wi], N = a.N[wi];
            const int nbx = N >> 5;
            const int n0 = (bid % nbx)*32, k0 = (bid / nbx)*32;
            const int r = tid >> 3, c4 = (tid & 7)*4;
            float4 v = *(const float4*)&W[(size_t)(k0+r)*N + n0 + c4];
            t[r][c4+0]=v.x; t[r][c4+1]=v.y; t[r][c4+2]=v.z; t[r][c4+3]=v.w;
            __syncthreads();
            ushort4 o;
            o.x = f2bf(t[c4+0][r]); o.y = f2bf(t[c4+1][r]);
            o.z = f2bf(t[c4+2][r]); o.w = f2bf(t[c4+3][r]);
            *(ushort4*)&Wt[(size_t)(n0+r)*K + k0 + c4] = o;
            return;
        }
        bid -= a.nblk[wi];
    }
}

// LayerNorm over 768, bf16 output. Optional fused residual add (in += add -> resid).
__global__ __launch_bounds__(256) void k_ln(const float* __restrict__ in,
                                            const float* __restrict__ add,
                                            const float* __restrict__ g,
                                            const float* __restrict__ beta,
                                            unsigned short* __restrict__ out,
                                            float* __restrict__ resid,
                                            int nvalid) {
    int r = blockIdx.x;
    int tid = threadIdx.x;
    const size_t base = (size_t)r*D0;
    if (r >= nvalid) {
        out[base+tid] = 0; out[base+tid+256] = 0; out[base+tid+512] = 0;
        return;
    }
    float v0 = in[base+tid], v1 = in[base+tid+256], v2 = in[base+tid+512];
    if (add) {
        v0 += add[base+tid]; v1 += add[base+tid+256]; v2 += add[base+tid+512];
        resid[base+tid] = v0; resid[base+tid+256] = v1; resid[base+tid+512] = v2;
    }
    float s = v0+v1+v2;
    float ss = v0*v0 + v1*v1 + v2*v2;
    #pragma unroll
    for (int o = 32; o >= 1; o >>= 1) {
        s  += __shfl_down(s, o);
        ss += __shfl_down(ss, o);
    }
    __shared__ float red[8];
    __shared__ float mv[2];
    int w = tid >> 6;
    if ((tid & 63) == 0) { red[w] = s; red[4+w] = ss; }
    __syncthreads();
    if (tid == 0) {
        float S1 = red[0]+red[1]+red[2]+red[3];
        float S2 = red[4]+red[5]+red[6]+red[7];
        float mean = S1 * (1.f/D0);
        float var  = S2 * (1.f/D0) - mean*mean;
        mv[0] = mean; mv[1] = rsqrtf(var + 1e-5f);
    }
    __syncthreads();
    float mean = mv[0], rstd = mv[1];
    out[base+tid]     = f2bf((v0-mean)*rstd*g[tid]     + beta[tid]);
    out[base+tid+256] = f2bf((v1-mean)*rstd*g[tid+256] + beta[tid+256]);
    out[base+tid+512] = f2bf((v2-mean)*rstd*g[tid+512] + beta[tid+512]);
}

// bf16 MFMA GEMM body, 64x64 tile / BK=64: C = A[M,K] @ Bt[N,K]^T + bias.
// 4 waves 2x2, each 32x32 out (2x2 frags). LDS chunk-XOR swizzle by row&7 on
// BOTH global_load_lds source and ds_read (rule #21 involution).
template<int GELU, int OUTBF>
__device__ __forceinline__ void gemm64_body(unsigned short* As, unsigned short* Bs,
                                            const unsigned short* __restrict__ A,
                                            const unsigned short* __restrict__ Bt,
                                            const float* __restrict__ bias,
                                            void* __restrict__ Cv,
                                            int N, int K, int bx, int by) {
    const int tid = threadIdx.x;
    const int w = tid >> 6;
    const int l = tid & 63;
    const int wm = w >> 1, wn = w & 1;
    const int m0 = by * 64, n0 = bx * 64;

    f32x4 acc[2][2] = {};

    for (int k0 = 0; k0 < K; k0 += 64) {
        __syncthreads();
        #pragma unroll
        for (int i = 0; i < 2; ++i) {
            int s = i*256 + tid;             // 16B slot 0..511
            int row = s >> 3;
            int ch  = (s & 7) ^ (row & 7);   // logical k-chunk stored at this slot
            const unsigned short* ga = A  + (size_t)(m0 + row)*K + k0 + ch*8;
            const unsigned short* gb = Bt + (size_t)(n0 + row)*K + k0 + ch*8;
            lptr_t la = (lptr_t)(As + (i*256 + w*64)*8);   // wave-uniform base
            lptr_t lb = (lptr_t)(Bs + (i*256 + w*64)*8);
            __builtin_amdgcn_global_load_lds((gptr_t)ga, la, 16, 0, 0);
            __builtin_amdgcn_global_load_lds((gptr_t)gb, lb, 16, 0, 0);
        }
        __syncthreads();
        #pragma unroll
        for (int kc = 0; kc < 2; ++kc) {
            const int kchunk = kc*4 + (l >> 4);
            bf16x8 a[2], b[2];
            #pragma unroll
            for (int mi = 0; mi < 2; ++mi) {
                int row = wm*32 + mi*16 + (l & 15);
                a[mi] = *(const bf16x8*)&As[row*64 + ((kchunk ^ (row & 7))*8)];
            }
            #pragma unroll
            for (int ni = 0; ni < 2; ++ni) {
                int row = wn*32 + ni*16 + (l & 15);
                b[ni] = *(const bf16x8*)&Bs[row*64 + ((kchunk ^ (row & 7))*8)];
            }
            #pragma unroll
            for (int mi = 0; mi < 2; ++mi)
                #pragma unroll
                for (int ni = 0; ni < 2; ++ni)
                    acc[mi][ni] = __builtin_amdgcn_mfma_f32_16x16x32_bf16(a[mi], b[ni], acc[mi][ni], 0, 0, 0);
        }
    }

    // Epilogue. C/D layout (HW-verified): col = lane&15, row = (lane>>4)*4 + reg.
    float* Cf = (float*)Cv;
    unsigned short* Cb = (unsigned short*)Cv;
    const int rbase = m0 + wm*32 + (l >> 4)*4;
    const int cbase = n0 + wn*32 + (l & 15);
    #pragma unroll
    for (int ni = 0; ni < 2; ++ni) {
        int col = cbase + ni*16;
        float bv = bias[col];
        #pragma unroll
        for (int mi = 0; mi < 2; ++mi) {
            #pragma unroll
            for (int r = 0; r < 4; ++r) {
                int row = rbase + mi*16 + r;
                float v = acc[mi][ni][r] + bv;
                if (GELU) v = gelu_new(v);
                if (OUTBF) Cb[(size_t)row*N + col] = f2bf(v);
                else       Cf[(size_t)row*N + col] = v;
            }
        }
    }
}

template<int GELU, int OUTBF>
__global__ __launch_bounds__(256) void k_gemm64(const unsigned short* __restrict__ A,
                                                const unsigned short* __restrict__ Bt,
                                                const float* __restrict__ bias,
                                                void* __restrict__ Cv,
                                                int N, int K) {
    __shared__ unsigned short As[64*64];
    __shared__ unsigned short Bs[64*64];
    gemm64_body<GELU,OUTBF>(As, Bs, A, Bt, bias, Cv, N, K, blockIdx.x, blockIdx.y);
}

// Merged qkv (1224 blocks) + ckv (192 blocks) in one launch: fills CUs better.
__global__ __launch_bounds__(256) void k_gemm_qkvckv(const unsigned short* __restrict__ hlb,
                                                     const unsigned short* __restrict__ WatT,
                                                     const float* __restrict__ bat,
                                                     unsigned short* __restrict__ qkvb,
                                                     const unsigned short* __restrict__ ctxb,
                                                     const unsigned short* __restrict__ WrefT,
                                                     const float* __restrict__ bref,
                                                     unsigned short* __restrict__ ckvb) {
    __shared__ unsigned short As[64*64];
    __shared__ unsigned short Bs[64*64];
    int bid = blockIdx.x;
    if (bid < (2304/64)*(TP/64)) {
        gemm64_body<0,1>(As, Bs, hlb, WatT, bat, qkvb, 2304, 768, bid % (2304/64), bid / (2304/64));
    } else {
        bid -= (2304/64)*(TP/64);
        gemm64_body<0,1>(As, Bs, ctxb, WrefT, bref, ckvb, 1536, 768, bid % (1536/64), bid / (1536/64));
    }
}

// ---------------- MFMA flash attention (occupancy-oriented) ----------------
// Block: 64 q rows x one (b,h); 4 waves, each one 16-row m-tile. Grid 17x24.
// q-tiles reversed so heavy (high-q0) blocks launch first.
__global__ __launch_bounds__(256, 2) void k_attn_mfma(const unsigned short* __restrict__ qkvb,
                                                      const unsigned short* __restrict__ ckvb,
                                                      unsigned short* __restrict__ attnob) {
    const int bh = blockIdx.y;
    const int b = bh / NH, hh = bh % NH;
    const int tid = threadIdx.x;
    const int w = tid >> 6;
    const int l = tid & 63;
    const int lg = l >> 4;       // 0..3
    const int ll = l & 15;

    const int q0 = (16 - blockIdx.x) * 64;   // reversed: heavy blocks first
    const int qw = q0 + w*16;

    __shared__ unsigned short Ks[64*64];      // [key][dh], chunk-swz by key&7
    __shared__ unsigned short Vt[64*64];      // [d][kv],  chunk-swz by d&7
    __shared__ unsigned short Ps[4][16*64];   // per-wave [q][kv], chunk-swz by q&7

    // Q fragments: lane holds Q[q=qw+ll][kc*32 + lg*8 .. +8]
    bf16x8 qf[2];
    {
        int qc = min(qw + ll, ND-1);
        const unsigned short* qrow = qkvb + (size_t)(b*ND + qc)*2304 + hh*64;
        qf[0] = *(const bf16x8*)(qrow + lg*8);
        qf[1] = *(const bf16x8*)(qrow + 32 + lg*8);
    }

    f32x4 o_acc[4] = {};
    float mrow[4], lrow[4];
    #pragma unroll
    for (int i = 0; i < 4; ++i) { mrow[i] = -1e30f; lrow[i] = 0.f; }

    const int qmax_blk = min(q0 + 63, ND-1);
    const int ntiles = (qmax_blk + SCX)/64 + 1;
    const int klim_wave = qw + 15 + SCX;

    for (int kt = 0; kt < ntiles; ++kt) {
        __syncthreads();   // previous tile's LDS reads done
        // ---- stage K via global_load_lds, pre-swizzled source (2 instr/thread-set)
        #pragma unroll
        for (int it = 0; it < 2; ++it) {
            int slot = it*256 + tid;              // 16B slot 0..511
            int key  = slot >> 3;
            int ch   = (slot & 7) ^ (key & 7);
            int kg   = min(kt*64 + key, NS-1);
            const unsigned short* src;
            if (kg < SCX) src = ckvb + (size_t)(b*SCX + kg)*1536 + hh*64 + ch*8;
            else          src = qkvb + (size_t)(b*ND + kg - SCX)*2304 + 768 + hh*64 + ch*8;
            __builtin_amdgcn_global_load_lds((gptr_t)src, (lptr_t)(Ks + (size_t)(it*256 + w*64)*8), 16, 0, 0);
        }
        // ---- stage V transposed; lane map kv0=(tid&31)*2, dch=tid>>5 -> 2-way banks
        {
            int kv0 = (tid & 31)*2;
            int dch = tid >> 5;
            int kg0 = min(kt*64 + kv0,     NS-1);
            int kg1 = min(kt*64 + kv0 + 1, NS-1);
            const unsigned short* s0 = (kg0 < SCX)
                ? ckvb + (size_t)(b*SCX + kg0)*1536 + 768 + hh*64 + dch*8
                : qkvb + (size_t)(b*ND + kg0 - SCX)*2304 + 1536 + hh*64 + dch*8;
            const unsigned short* s1 = (kg1 < SCX)
                ? ckvb + (size_t)(b*SCX + kg1)*1536 + 768 + hh*64 + dch*8
                : qkvb + (size_t)(b*ND + kg1 - SCX)*2304 + 1536 + hh*64 + dch*8;
            union { uint4 u; unsigned short s[8]; } r0, r1;
            r0.u = *(const uint4*)s0;
            r1.u = *(const uint4*)s1;
            #pragma unroll
            for (int i = 0; i < 8; ++i) {
                int d = dch*8 + i;
                unsigned val = (unsigned)r0.s[i] | ((unsigned)r1.s[i] << 16);
                *(unsigned*)((char*)Vt + d*128 + (((kv0>>3) ^ (d&7))*16) + ((kv0&7)*2)) = val;
            }
        }
        __syncthreads();   // drains vmcnt (global_load_lds) + lgkm (ds writes)

        if (kt*64 > klim_wave) continue;   // wave-uniform: fully masked tile

        // ---- S = Q K^T
        bf16x8 kf[4][2];
        #pragma unroll
        for (int c = 0; c < 4; ++c) {
            int key = c*16 + ll;
            #pragma unroll
            for (int kc = 0; kc < 2; ++kc)
                kf[c][kc] = *(const bf16x8*)((char*)Ks + key*128 + (((kc*4 + lg) ^ (key&7))*16));
        }
        f32x4 s_acc[4];
        #pragma unroll
        for (int c = 0; c < 4; ++c) {
            f32x4 z = {0.f, 0.f, 0.f, 0.f};
            z = __builtin_amdgcn_mfma_f32_16x16x32_bf16(qf[0], kf[c][0], z, 0, 0, 0);
            s_acc[c] = __builtin_amdgcn_mfma_f32_16x16x32_bf16(qf[1], kf[c][1], z, 0, 0, 0);
        }

        // ---- mask (boundary tiles only)
        const int kbase = kt*64;
        if (kbase + 63 > qw + SCX) {
            #pragma unroll
            for (int c = 0; c < 4; ++c) {
                int key = kbase + c*16 + ll;
                #pragma unroll
                for (int i = 0; i < 4; ++i) {
                    int q = qw + lg*4 + i;
                    if (key > q + SCX) s_acc[c][i] = -1e30f;
                }
            }
        }

        // ---- online softmax (row r = lg*4+i; reduce over 16 ll lanes)
        float tmax[4];
        #pragma unroll
        for (int i = 0; i < 4; ++i) {
            float tm = fmaxf(fmaxf(s_acc[0][i], s_acc[1][i]),
                             fmaxf(s_acc[2][i], s_acc[3][i]));
            #pragma unroll
            for (int o = 1; o < 16; o <<= 1) tm = fmaxf(tm, __shfl_xor(tm, o));
            tmax[i] = tm;
        }
        #pragma unroll
        for (int i = 0; i < 4; ++i) {
            float mnew = fmaxf(mrow[i], tmax[i]*0.125f);
            float fs = __expf(mrow[i] - mnew);
            mrow[i] = mnew;
            lrow[i] *= fs;
            #pragma unroll
            for (int dc = 0; dc < 4; ++dc) o_acc[dc][i] *= fs;
        }
        float psum[4] = {0.f, 0.f, 0.f, 0.f};
        #pragma unroll
        for (int c = 0; c < 4; ++c) {
            int kv = c*16 + ll;
            #pragma unroll
            for (int i = 0; i < 4; ++i) {
                float p = __expf(fmaf(s_acc[c][i], 0.125f, -mrow[i]));
                psum[i] += p;
                int q = lg*4 + i;          // local row 0..15
                union { float f; unsigned u; } cv; cv.f = p;
                *(unsigned short*)((char*)Ps[w] + q*128 + (((kv>>3) ^ (q&7))*16) + ((kv&7)*2))
                    = (unsigned short)((cv.u + 0x8000u) >> 16);
            }
        }
        #pragma unroll
        for (int i = 0; i < 4; ++i) {
            float s = psum[i];
            #pragma unroll
            for (int o = 1; o < 16; o <<= 1) s += __shfl_xor(s, o);
            lrow[i] += s;
        }

        // ---- PV: O += P @ V  (A-frag from Ps, B-frag from Vt)
        #pragma unroll
        for (int kc = 0; kc < 2; ++kc) {
            int q = ll;
            bf16x8 pf = *(const bf16x8*)((char*)Ps[w] + q*128 + (((kc*4 + lg) ^ (q&7))*16));
            #pragma unroll
            for (int dc = 0; dc < 4; ++dc) {
                int d = dc*16 + ll;
                bf16x8 vf = *(const bf16x8*)((char*)Vt + d*128 + (((kc*4 + lg) ^ (d&7))*16));
                o_acc[dc] = __builtin_amdgcn_mfma_f32_16x16x32_bf16(pf, vf, o_acc[dc], 0, 0, 0);
            }
        }
    }

    // ---- epilogue: O / lsum -> bf16
    #pragma unroll
    for (int i = 0; i < 4; ++i) {
        int q = qw + lg*4 + i;
        if (q >= ND) continue;
        float inv = 1.f / lrow[i];
        unsigned short* orow = attnob + (size_t)(b*ND + q)*768 + hh*64;
        #pragma unroll
        for (int dc = 0; dc < 4; ++dc)
            orow[dc*16 + ll] = f2bf(o_acc[dc][i] * inv);
    }
}

// out[b,t,:] = h[b, t+1, :] + mproj[b, t+1, :]   (drop sos row)
__global__ void k_final(const float* __restrict__ h, const float* __restrict__ mp,
                        float* __restrict__ out) {
    int idx = blockIdx.x*blockDim.x + threadIdx.x;
    const int total = NB*SQ*192;
    if (idx >= total) return;
    int r = idx/192, c4 = idx%192;
    int b = r/SQ, t = r%SQ;
    size_t hr = (size_t)(b*ND + t + 1)*192 + c4;
    float4 hv = ((const float4*)h)[hr];
    float4 mv = ((const float4*)mp)[hr];
    ((float4*)out)[idx] = make_float4(hv.x+mv.x, hv.y+mv.y, hv.z+mv.z, hv.w+mv.w);
}

extern "C" void kernel_launch(void* const* d_in, const int* in_sizes, int n_in,
                              void* d_out, int out_size, void* d_ws, size_t ws_size,
                              hipStream_t stream) {
    const float* x     = (const float*)d_in[0];
    const float* ctx   = (const float*)d_in[1];
    const float* sos   = (const float*)d_in[2];
    const float* ln1g  = (const float*)d_in[3];
    const float* ln1b  = (const float*)d_in[4];
    const float* Wat   = (const float*)d_in[5];
    const float* bat   = (const float*)d_in[6];
    const float* Wref  = (const float*)d_in[7];
    const float* bref  = (const float*)d_in[8];
    const float* Wpj   = (const float*)d_in[9];
    const float* bpj   = (const float*)d_in[10];
    const float* ln2g  = (const float*)d_in[11];
    const float* ln2b  = (const float*)d_in[12];
    const float* Wfc   = (const float*)d_in[13];
    const float* bfc   = (const float*)d_in[14];
    const float* Wmp   = (const float*)d_in[15];
    const float* bmp   = (const float*)d_in[16];
    float* out = (float*)d_out;

    char* p = (char*)d_ws;
    float* h      = (float*)p;  p += (size_t)TP*768*4;
    float* aproj  = (float*)p;  p += (size_t)TP*768*4;
    unsigned short* qkvb   = (unsigned short*)p;  p += (size_t)TP*2304*2;
    unsigned short* ckvb   = (unsigned short*)p;  p += (size_t)TC*1536*2;
    unsigned short* hlb    = (unsigned short*)p;  p += (size_t)TP*768*2;
    unsigned short* attnob = (unsigned short*)p;  p += (size_t)TP*768*2;
    unsigned short* mfcb   = (unsigned short*)p;  p += (size_t)TP*3072*2;
    unsigned short* ctxb   = (unsigned short*)p;  p += (size_t)TC*768*2;
    unsigned short* WatT   = (unsigned short*)p;  p += (size_t)2304*768*2;
    unsigned short* WrefT  = (unsigned short*)p;  p += (size_t)1536*768*2;
    unsigned short* WpjT   = (unsigned short*)p;  p += (size_t)768*768*2;
    unsigned short* WfcT   = (unsigned short*)p;  p += (size_t)3072*768*2;
    unsigned short* WmpT   = (unsigned short*)p;  p += (size_t)768*3072*2;

    PrepArgs pa;
    pa.x = x; pa.sos = sos; pa.h = h; pa.ctx = ctx; pa.ctxb = ctxb;
    pa.W[0]=Wat;  pa.Wt[0]=WatT;  pa.K[0]=768;  pa.N[0]=2304; pa.nblk[0]=(2304/32)*(768/32);
    pa.W[1]=Wref; pa.Wt[1]=WrefT; pa.K[1]=768;  pa.N[1]=1536; pa.nblk[1]=(1536/32)*(768/32);
    pa.W[2]=Wpj;  pa.Wt[2]=WpjT;  pa.K[2]=768;  pa.N[2]=768;  pa.nblk[2]=(768/32)*(768/32);
    pa.W[3]=Wfc;  pa.Wt[3]=WfcT;  pa.K[3]=768;  pa.N[3]=3072; pa.nblk[3]=(3072/32)*(768/32);
    pa.W[4]=Wmp;  pa.Wt[4]=WmpT;  pa.K[4]=3072; pa.N[4]=768;  pa.nblk[4]=(768/32)*(3072/32);
    int nprep = NBH + NCVT + pa.nblk[0]+pa.nblk[1]+pa.nblk[2]+pa.nblk[3]+pa.nblk[4];

    k_prep<<<dim3(nprep), dim3(256), 0, stream>>>(pa);
    k_ln<<<dim3(TP), dim3(256), 0, stream>>>(h, nullptr, ln1g, ln1b, hlb, nullptr, TT);
    k_gemm_qkvckv<<<dim3((2304/64)*(TP/64) + (1536/64)*(TC/64)), dim3(256), 0, stream>>>(
        hlb, WatT, bat, qkvb, ctxb, WrefT, bref, ckvb);
    k_attn_mfma<<<dim3(17, NB*NH), dim3(256), 0, stream>>>(qkvb, ckvb, attnob);
    k_gemm64<0,0><<<dim3(768/64, TP/64), dim3(256), 0, stream>>>(attnob, WpjT, bpj, aproj, 768, 768);
    k_ln<<<dim3(TP), dim3(256), 0, stream>>>(h, aproj, ln2g, ln2b, hlb, h, TT);
    k_gemm64<1,1><<<dim3(3072/64, TP/64), dim3(256), 0, stream>>>(hlb, WfcT, bfc, mfcb, 3072, 768);
    k_gemm64<0,0><<<dim3(768/64, TP/64), dim3(256), 0, stream>>>(mfcb, WmpT, bmp, aproj, 768, 3072);
    k_final<<<dim3((NB*SQ*192 + 255)/256), dim3(256), 0, stream>>>(h, aproj, out);
}